// Round 8
// baseline (854.185 us; speedup 1.0000x reference)
//
#include <hip/hip_runtime.h>

#define DD 128      // GNN_DIM == NODE_FEAT
#define HDIM 512    // H * D
#define EFEAT 32
#define NHEAD 4

typedef short s16x8 __attribute__((ext_vector_type(8)));
typedef float f32x4 __attribute__((ext_vector_type(4)));

__device__ __forceinline__ float lrelu(float x){ return x > 0.f ? x : 0.2f*x; }

__device__ __forceinline__ unsigned short f2bf(float f){
  unsigned u = __float_as_uint(f);
  unsigned r = (u + 0x7FFFu + ((u >> 16) & 1u)) >> 16;
  return (unsigned short)r;
}
__device__ __forceinline__ float bf2f(unsigned short u){
  return __uint_as_float(((unsigned)u) << 16);
}

__device__ __forceinline__ float waveReduceSum(float v){
  #pragma unroll
  for (int m = 1; m < 64; m <<= 1) v += __shfl_xor(v, m, 64);
  return v;
}
__device__ __forceinline__ float waveReduceMax(float v){
  #pragma unroll
  for (int m = 1; m < 64; m <<= 1) v = fmaxf(v, __shfl_xor(v, m, 64));
  return v;
}
__device__ __forceinline__ float quadReduceSum(float v){
  v += __shfl_xor(v, 1, 64); v += __shfl_xor(v, 2, 64);
  v += __shfl_xor(v, 4, 64); v += __shfl_xor(v, 8, 64);
  return v;
}

// ---------------- edge-attr column sums (float4, saturating grid) ----------------
__global__ __launch_bounds__(256) void ea_sum4_kernel(const float* __restrict__ ea,
                                                      float* __restrict__ ea_sum, int E){
  __shared__ float s[EFEAT];
  int t = threadIdx.x;
  if (t < EFEAT) s[t] = 0.f;
  __syncthreads();
  int nvec = E*8;
  float4 acc = make_float4(0.f, 0.f, 0.f, 0.f);
  for (int i = blockIdx.x*256 + t; i < nvec; i += gridDim.x*256){
    float4 v = *((const float4*)ea + i);
    acc.x += v.x; acc.y += v.y; acc.z += v.z; acc.w += v.w;
  }
  int cg = (t & 7)*4;
  atomicAdd(&s[cg + 0], acc.x); atomicAdd(&s[cg + 1], acc.y);
  atomicAdd(&s[cg + 2], acc.z); atomicAdd(&s[cg + 3], acc.w);
  __syncthreads();
  if (t < EFEAT) atomicAdd(&ea_sum[t], s[t]);
}

// ---------------- CSR build over dst ----------------
__global__ void hist_kernel(const int* __restrict__ dst, int* __restrict__ deg, int E){
  int e = blockIdx.x*blockDim.x + threadIdx.x;
  if (e < E) atomicAdd(&deg[dst[e]], 1);
}

__global__ void scan_kernel(const int* __restrict__ deg, int* __restrict__ offs, int N){
  __shared__ int s[1024];
  int t = threadIdx.x;
  int chunk = (N + 1023) >> 10;
  int b = t*chunk, e = min(b + chunk, N);
  int sum = 0;
  for (int i = b; i < e; i++) sum += deg[i];
  s[t] = sum;
  __syncthreads();
  for (int d = 1; d < 1024; d <<= 1){
    int x = (t >= d) ? s[t - d] : 0;
    __syncthreads();
    s[t] += x;
    __syncthreads();
  }
  int run = s[t] - sum;
  for (int i = b; i < e; i++){ offs[i] = run; run += deg[i]; }
  if (t == 1023) offs[N] = s[1023];
}

__global__ void scatter_kernel(const int* __restrict__ dst, const int* __restrict__ src,
                               int* __restrict__ cursor, int* __restrict__ eid,
                               int* __restrict__ srcp, int* __restrict__ dstp,
                               int* __restrict__ posOf, int E){
  int e = blockIdx.x*blockDim.x + threadIdx.x;
  if (e < E){
    int d = dst[e];
    int p = atomicAdd(&cursor[d], 1);
    eid[p] = e;
    srcp[p] = src[e];
    dstp[p] = d;
    posOf[e] = p;
  }
}

// ---------------- permute+convert edge attrs into CSR order (bf16, float4) ------------
__global__ void eap_prep_kernel(const float* __restrict__ ea, const int* __restrict__ eid,
                                unsigned short* __restrict__ eap, int E){
  int idx = blockIdx.x*blockDim.x + threadIdx.x;
  int p = idx >> 3, q = idx & 7;
  if (p >= E) return;
  float4 v = *((const float4*)(ea + (size_t)eid[p]*EFEAT) + q);
  ushort4 u = make_ushort4(f2bf(v.x), f2bf(v.y), f2bf(v.z), f2bf(v.w));
  *((ushort4*)(eap + (size_t)p*EFEAT) + q) = u;
}

// ---------------- fp32 -> bf16 convert (float4 -> ushort4) ----------------
__global__ void bf16_conv_kernel(const float* __restrict__ in,
                                 unsigned short* __restrict__ out, int nvec){
  int i = blockIdx.x*blockDim.x + threadIdx.x;
  if (i >= nvec) return;
  float4 v = *((const float4*)in + i);
  *((ushort4*)out + i) = make_ushort4(f2bf(v.x), f2bf(v.y), f2bf(v.z), f2bf(v.w));
}

// ---------------- parallel folds: wave per output ----------------
__global__ __launch_bounds__(256) void fold_ws_kernel(const float* __restrict__ gat_W,
    const float* __restrict__ att_src, const float* __restrict__ att_dst,
    float* __restrict__ ws_att, int L){
  int wave = threadIdx.x >> 6, lane = threadIdx.x & 63;
  int idx = blockIdx.x*4 + wave;
  if (idx >= L*DD*8) return;
  int j = idx & 7; int k = (idx >> 3) & 127; int l = idx >> 10;
  int h = j & 3;
  const float* att = (j < 4) ? att_src : att_dst;
  const float* av = att + (size_t)(l*NHEAD + h)*DD;
  const float* Wl = gat_W + (size_t)l*DD*HDIM + (size_t)k*HDIM + h*DD;
  float acc = Wl[lane]*av[lane] + Wl[lane + 64]*av[lane + 64];
  acc = waveReduceSum(acc);
  if (lane == 0) ws_att[idx] = acc;
}

__global__ __launch_bounds__(256) void fold_we_kernel(const float* __restrict__ gat_We,
    const float* __restrict__ att_edge, float* __restrict__ we_att, int L){
  int wave = threadIdx.x >> 6, lane = threadIdx.x & 63;
  int idx = blockIdx.x*4 + wave;
  if (idx >= L*EFEAT*NHEAD) return;
  int h = idx & 3; int f = (idx >> 2) & 31; int l = idx >> 7;
  const float* av = att_edge + (size_t)(l*NHEAD + h)*DD;
  const float* Wel = gat_We + (size_t)l*EFEAT*HDIM + (size_t)f*HDIM + h*DD;
  float acc = Wel[lane]*av[lane] + Wel[lane + 64]*av[lane + 64];
  acc = waveReduceSum(acc);
  if (lane == 0) we_att[idx] = acc;
}

__global__ void fold_self_kernel(const float* __restrict__ we_att,
    const float* __restrict__ ea_sum, float invE, float* __restrict__ al_self, int L){
  int t = threadIdx.x;
  if (t >= L*NHEAD) return;
  int h = t & 3; int l = t >> 2;
  float acc = 0.f;
  for (int f = 0; f < EFEAT; f++) acc += ea_sum[f]*invE * we_att[(l*EFEAT + f)*NHEAD + h];
  al_self[t] = acc;
}

// ---------------- transpose+convert gat_W to bf16 Bt[l][n=128][k=512] ----------------
__global__ void bt_prep_kernel(const float* __restrict__ gat_W,
                               unsigned short* __restrict__ Bt, int total){
  int i = blockIdx.x*blockDim.x + threadIdx.x;
  if (i >= total) return;
  int l = i >> 16; int rem = i & 65535;
  int d = rem >> 9; int kk = rem & 511;
  int k = kk & 127; int h = kk >> 7;
  Bt[i] = f2bf(gat_W[(size_t)l*DD*HDIM + (size_t)k*HDIM + h*DD + d]);
}

// ---------------- embW -> bf16 transposed [128][128] ----------------
__global__ void embwt_prep_kernel(const float* __restrict__ embW,
                                  unsigned short* __restrict__ Wt){
  int i = blockIdx.x*blockDim.x + threadIdx.x;
  if (i >= DD*DD) return;
  int n = i >> 7, k = i & 127;
  Wt[i] = f2bf(embW[(size_t)k*DD + n]);
}

// ---------------- [W1a | W1b] -> bf16 transposed [256][128] ----------------
__global__ void w1ab_prep_kernel(const float* __restrict__ hW1,
                                 unsigned short* __restrict__ Bhd){
  int i = blockIdx.x*blockDim.x + threadIdx.x;
  if (i >= 256*DD) return;
  int n = i >> 7, k = i & 127;
  float v = (n < 128) ? hW1[(size_t)k*DD + n] : hW1[(size_t)(128 + k)*DD + (n - 128)];
  Bhd[i] = f2bf(v);
}

// ---------------- W1c -> MFMA B-fragment layout: Bh[c][lane][j] ----------------
__global__ void w1c_prep_kernel(const float* __restrict__ W1c, unsigned short* __restrict__ Bh){
  int i = blockIdx.x*blockDim.x + threadIdx.x;
  if (i >= 8*64*8) return;
  int j = i & 7, lane = (i >> 3) & 63, c = i >> 9;
  int ln15 = lane & 15, quad = lane >> 4;
  int k = quad*8 + j, n = c*16 + ln15;
  Bh[i] = f2bf(W1c[(size_t)k*DD + n]);
}

// ---------------- unified MFMA GEMM + fused epilogues ----------------
// C_acc = scale * A[N,KD] @ Bt^T + bias   (Bt is [NOUT][KD], bf16)
// A-fragments prefetched to registers (MLP); s_att stored transposed (no bank conflicts).
template<int KD, int NOUT>
__global__ __launch_bounds__(256, 2) void gemm_fused_kernel(
    const unsigned short* __restrict__ A, const unsigned short* __restrict__ Bt,
    const float* __restrict__ bias, float scale, int relu, int mode,
    const float* __restrict__ ln_scale, const float* __restrict__ ln_bias,
    const float* __restrict__ gamma, const float* __restrict__ beta,
    const float* __restrict__ ws_att,
    unsigned short* __restrict__ hm_bf, float* __restrict__ al_s,
    float* __restrict__ al_d, unsigned short* __restrict__ outbf, int N){
  constexpr int NC = NOUT/16;
  constexpr int KS = KD/32;
  __shared__ float s_att[8*DD];   // transposed: s_att[j*DD + col]
  __shared__ float sP[4][DD];
  int t = threadIdx.x;
  if (mode == 0){
    for (int i = t; i < DD*8; i += 256){
      int col = i & 127, j = i >> 7;
      s_att[j*DD + col] = ws_att[col*8 + j];
    }
    for (int i = t; i < DD; i += 256){
      sP[0][i] = ln_scale[i]; sP[1][i] = ln_bias[i];
      sP[2][i] = gamma[i];    sP[3][i] = beta[i];
    }
    __syncthreads();
  }
  int wave = t >> 6, lane = t & 63;
  int ln15 = lane & 15, quad = lane >> 4;
  int row0 = blockIdx.x*64 + wave*16;
  int arow = row0 + ln15;
  if (arow > N - 1) arow = N - 1;
  const unsigned short* aptr = A + (size_t)arow*KD + quad*8;

  // prefetch ALL a-fragments (independent loads -> high MLP)
  s16x8 af[KS];
  #pragma unroll
  for (int ks = 0; ks < KS; ks++) af[ks] = *(const s16x8*)(aptr + ks*32);

  f32x4 acc[NC];
  #pragma unroll
  for (int c = 0; c < NC; c++) acc[c] = (f32x4)(0.f);

  #pragma unroll
  for (int ks = 0; ks < KS; ks++){
    #pragma unroll
    for (int c = 0; c < NC; c++){
      s16x8 b = *(const s16x8*)(Bt + (size_t)(c*16 + ln15)*KD + quad*8 + ks*32);
      acc[c] = __builtin_amdgcn_mfma_f32_16x16x32_bf16(af[ks], b, acc[c], 0, 0, 0);
    }
  }

  float bv[NC];
  #pragma unroll
  for (int c = 0; c < NC; c++){
    if constexpr (NOUT == 256) bv[c] = (c < 8) ? bias[c*16 + ln15] : 0.f;
    else bv[c] = bias[c*16 + ln15];
  }

  #pragma unroll
  for (int r = 0; r < 4; r++){
    int row = row0 + quad*4 + r;
    bool valid = (row < N);
    float hv[NC];
    #pragma unroll
    for (int c = 0; c < NC; c++){
      float v = scale*acc[c][r] + bv[c];
      hv[c] = relu ? fmaxf(v, 0.f) : v;
    }
    if (mode == 1){
      if (valid){
        #pragma unroll
        for (int c = 0; c < NC; c++)
          outbf[(size_t)row*NOUT + c*16 + ln15] = f2bf(hv[c]);
      }
      continue;
    }
    if constexpr (NOUT == 128){
      float sum = 0.f;
      #pragma unroll
      for (int c = 0; c < NC; c++) sum += hv[c];
      sum = quadReduceSum(sum);
      float mu = sum * (1.f/128.f);
      float vs = 0.f;
      #pragma unroll
      for (int c = 0; c < NC; c++){ float d = hv[c] - mu; vs += d*d; }
      vs = quadReduceSum(vs);
      float rstd = rsqrtf(vs*(1.f/128.f) + 1e-5f);
      float m[NC];
      #pragma unroll
      for (int c = 0; c < NC; c++){
        int col = c*16 + ln15;
        float hn = (hv[c] - mu)*rstd*sP[0][col] + sP[1][col];
        m[c] = sP[2][col]*hn + sP[3][col];
        if (valid) hm_bf[(size_t)row*DD + col] = f2bf(m[c]);
      }
      float alv[8];
      #pragma unroll
      for (int j = 0; j < 8; j++){
        float a = 0.f;
        #pragma unroll
        for (int c = 0; c < NC; c++) a += m[c]*s_att[j*DD + c*16 + ln15];
        alv[j] = quadReduceSum(a);
      }
      if (ln15 == 0 && valid){
        *(float4*)&al_s[(size_t)row*4] = make_float4(alv[0], alv[1], alv[2], alv[3]);
        *(float4*)&al_d[(size_t)row*4] = make_float4(alv[4], alv[5], alv[6], alv[7]);
      }
    }
  }
}

// ---------------- edge-parallel attention logits in CSR order ----------------
__global__ __launch_bounds__(256) void edge_logit_kernel(
    const unsigned short* __restrict__ eap, const float* __restrict__ al_s,
    const float* __restrict__ al_d, const int* __restrict__ srcp,
    const int* __restrict__ dstp, const float* __restrict__ we_att,
    float* __restrict__ abuf, int E){
  __shared__ float4 swe[EFEAT];
  int t = threadIdx.x;
  if (t < EFEAT) swe[t] = *(const float4*)&we_att[t*4];
  __syncthreads();
  int p = blockIdx.x*256 + t;
  if (p >= E) return;
  int s = srcp[p], d = dstp[p];
  float4 as = *(const float4*)&al_s[(size_t)s*4];
  float4 ad = *(const float4*)&al_d[(size_t)d*4];
  float a0 = as.x + ad.x, a1 = as.y + ad.y, a2 = as.z + ad.z, a3 = as.w + ad.w;
  const uint4* ep = (const uint4*)(eap + (size_t)p*EFEAT);
  #pragma unroll
  for (int q = 0; q < 4; q++){
    uint4 u = ep[q];
    unsigned arr[4] = {u.x, u.y, u.z, u.w};
    #pragma unroll
    for (int j = 0; j < 4; j++){
      float x0 = bf2f((unsigned short)(arr[j] & 0xffff));
      float x1 = bf2f((unsigned short)(arr[j] >> 16));
      float4 w0 = swe[q*8 + j*2], w1 = swe[q*8 + j*2 + 1];
      a0 += x0*w0.x + x1*w1.x;
      a1 += x0*w0.y + x1*w1.y;
      a2 += x0*w0.z + x1*w1.z;
      a3 += x0*w0.w + x1*w1.w;
    }
  }
  *(float4*)&abuf[(size_t)p*4] = make_float4(lrelu(a0), lrelu(a1), lrelu(a2), lrelu(a3));
}

// ---------------- fused softmax + aggregation (block per node, 64 threads) ------------
__global__ __launch_bounds__(64) void aggregate3_kernel(
    const unsigned short* __restrict__ hm_bf, const float* __restrict__ abuf,
    const float* __restrict__ al_s, const float* __restrict__ al_d,
    const float* __restrict__ al_self4, const int* __restrict__ offs,
    const int* __restrict__ srcp, unsigned short* __restrict__ z, int N){
  int n = blockIdx.x, t = threadIdx.x;
  int beg = offs[n], end = offs[n + 1];
  float4 aslf = *(const float4*)al_self4;
  float4 asn = *(const float4*)&al_s[(size_t)n*4];
  float4 adn = *(const float4*)&al_d[(size_t)n*4];
  float s0 = lrelu(asn.x + adn.x + aslf.x);
  float s1 = lrelu(asn.y + adn.y + aslf.y);
  float s2 = lrelu(asn.z + adn.z + aslf.z);
  float s3 = lrelu(asn.w + adn.w + aslf.w);
  float m0 = s0, m1 = s1, m2 = s2, m3 = s3;
  for (int p = beg + t; p < end; p += 64){
    float4 a = *(const float4*)&abuf[(size_t)p*4];
    m0 = fmaxf(m0, a.x); m1 = fmaxf(m1, a.y);
    m2 = fmaxf(m2, a.z); m3 = fmaxf(m3, a.w);
  }
  m0 = waveReduceMax(m0); m1 = waveReduceMax(m1);
  m2 = waveReduceMax(m2); m3 = waveReduceMax(m3);
  float e0 = __expf(s0 - m0), e1 = __expf(s1 - m1);
  float e2 = __expf(s2 - m2), e3 = __expf(s3 - m3);
  ushort2 hv = *((const ushort2*)(hm_bf + (size_t)n*DD) + t);
  float h0 = bf2f(hv.x), h1 = bf2f(hv.y);
  float ac00 = e0*h0, ac01 = e0*h1;
  float ac10 = e1*h0, ac11 = e1*h1;
  float ac20 = e2*h0, ac21 = e2*h1;
  float ac30 = e3*h0, ac31 = e3*h1;
  float den0 = e0, den1 = e1, den2 = e2, den3 = e3;
  int p = beg;
  for (; p + 2 <= end; p += 2){
    int sA = srcp[p], sB = srcp[p + 1];
    float4 aA = *(const float4*)&abuf[(size_t)p*4];
    float4 aB = *(const float4*)&abuf[(size_t)(p + 1)*4];
    ushort2 vA = *((const ushort2*)(hm_bf + (size_t)sA*DD) + t);
    ushort2 vB = *((const ushort2*)(hm_bf + (size_t)sB*DD) + t);
    float wA0 = __expf(aA.x - m0), wA1 = __expf(aA.y - m1);
    float wA2 = __expf(aA.z - m2), wA3 = __expf(aA.w - m3);
    float wB0 = __expf(aB.x - m0), wB1 = __expf(aB.y - m1);
    float wB2 = __expf(aB.z - m2), wB3 = __expf(aB.w - m3);
    float vA0 = bf2f(vA.x), vA1 = bf2f(vA.y);
    float vB0 = bf2f(vB.x), vB1 = bf2f(vB.y);
    ac00 += wA0*vA0 + wB0*vB0; ac01 += wA0*vA1 + wB0*vB1;
    ac10 += wA1*vA0 + wB1*vB0; ac11 += wA1*vA1 + wB1*vB1;
    ac20 += wA2*vA0 + wB2*vB0; ac21 += wA2*vA1 + wB2*vB1;
    ac30 += wA3*vA0 + wB3*vB0; ac31 += wA3*vA1 + wB3*vB1;
    den0 += wA0 + wB0; den1 += wA1 + wB1;
    den2 += wA2 + wB2; den3 += wA3 + wB3;
  }
  if (p < end){
    int s = srcp[p];
    float4 a = *(const float4*)&abuf[(size_t)p*4];
    ushort2 v2 = *((const ushort2*)(hm_bf + (size_t)s*DD) + t);
    float w0 = __expf(a.x - m0), w1 = __expf(a.y - m1);
    float w2 = __expf(a.z - m2), w3 = __expf(a.w - m3);
    float v0 = bf2f(v2.x), v1 = bf2f(v2.y);
    ac00 += w0*v0; ac01 += w0*v1;
    ac10 += w1*v0; ac11 += w1*v1;
    ac20 += w2*v0; ac21 += w2*v1;
    ac30 += w3*v0; ac31 += w3*v1;
    den0 += w0; den1 += w1; den2 += w2; den3 += w3;
  }
  float r0 = 1.f/(den0 + 1e-16f), r1 = 1.f/(den1 + 1e-16f);
  float r2 = 1.f/(den2 + 1e-16f), r3 = 1.f/(den3 + 1e-16f);
  size_t zb = (size_t)n*HDIM;
  ushort2* zp = (ushort2*)(z + zb);
  zp[0*64 + t] = make_ushort2(f2bf(ac00*r0), f2bf(ac01*r0));
  zp[1*64 + t] = make_ushort2(f2bf(ac10*r1), f2bf(ac11*r1));
  zp[2*64 + t] = make_ushort2(f2bf(ac20*r2), f2bf(ac21*r2));
  zp[3*64 + t] = make_ushort2(f2bf(ac30*r3), f2bf(ac31*r3));
}

// ---------------- MFMA edge head: out[e] = relu(p[s]+p[d]+ea@W1c)@W2 + b2 ------------
__global__ __launch_bounds__(256) void head_mfma_kernel(
    const unsigned short* __restrict__ eap, const int* __restrict__ posOf,
    const unsigned short* __restrict__ Bh, const unsigned short* __restrict__ pbuf,
    const float* __restrict__ W2, const float* __restrict__ b2,
    const int* __restrict__ srcA, const int* __restrict__ dstA,
    float* __restrict__ out, int E){
  int t = threadIdx.x;
  int wave = t >> 6, lane = t & 63;
  int ln15 = lane & 15, quad = lane >> 4;
  int e0 = (blockIdx.x*4 + wave)*16;
  if (e0 >= E) return;
  int arow = e0 + ln15;
  if (arow > E - 1) arow = E - 1;
  int ap = posOf[arow];
  s16x8 a = *(const s16x8*)(eap + (size_t)ap*EFEAT + quad*8);
  f32x4 acc[8];
  #pragma unroll
  for (int c = 0; c < 8; c++){
    s16x8 b = *(const s16x8*)(Bh + ((size_t)c*64 + lane)*8);
    acc[c] = __builtin_amdgcn_mfma_f32_16x16x32_bf16(a, b, (f32x4)(0.f), 0, 0, 0);
  }
  float w2v[8];
  #pragma unroll
  for (int c = 0; c < 8; c++) w2v[c] = W2[c*16 + ln15];
  float res[4];
  #pragma unroll
  for (int r = 0; r < 4; r++){
    int e = e0 + quad*4 + r;
    int ec = (e < E) ? e : E - 1;
    int s = srcA[ec], d = dstA[ec];
    const unsigned short* ps = pbuf + (size_t)s*256 + ln15;
    const unsigned short* pd = pbuf + (size_t)d*256 + 128 + ln15;
    float sum = 0.f;
    #pragma unroll
    for (int c = 0; c < 8; c++){
      float q = acc[c][r] + bf2f(ps[c*16]) + bf2f(pd[c*16]);
      sum += fmaxf(q, 0.f) * w2v[c];
    }
    res[r] = sum;
  }
  #pragma unroll
  for (int r = 0; r < 4; r++){
    float v = res[r];
    v += __shfl_xor(v, 1, 64); v += __shfl_xor(v, 2, 64);
    v += __shfl_xor(v, 4, 64); v += __shfl_xor(v, 8, 64);
    res[r] = v;
  }
  if (ln15 == 0){
    float bb = b2[0];
    #pragma unroll
    for (int r = 0; r < 4; r++){
      int e = e0 + quad*4 + r;
      if (e < E) out[e] = res[r] + bb;
    }
  }
}

extern "C" void kernel_launch(void* const* d_in, const int* in_sizes, int n_in,
                              void* d_out, int out_size, void* d_ws, size_t ws_size,
                              hipStream_t stream){
  const float* x      = (const float*)d_in[0];
  const int*   eidx   = (const int*)d_in[1];
  const float* eattr  = (const float*)d_in[2];
  const float* gamma  = (const float*)d_in[3];
  const float* beta   = (const float*)d_in[4];
  const float* embW   = (const float*)d_in[5];
  const float* embB   = (const float*)d_in[6];
  const float* lnS    = (const float*)d_in[7];
  const float* lnB    = (const float*)d_in[8];
  const float* gatW   = (const float*)d_in[9];
  const float* attS   = (const float*)d_in[10];
  const float* attD   = (const float*)d_in[11];
  const float* gatWe  = (const float*)d_in[12];
  const float* attE   = (const float*)d_in[13];
  const float* gatB   = (const float*)d_in[14];
  const float* hW1    = (const float*)d_in[15];
  const float* hB1    = (const float*)d_in[16];
  const float* hW2    = (const float*)d_in[17];
  const float* hB2    = (const float*)d_in[18];
  float* out = (float*)d_out;

  int N = in_sizes[0] / DD;
  int E = in_sizes[1] / 2;
  int L = in_sizes[3] / DD;
  int Npad = (N + 63) & ~63;

  const int* srcA = eidx;
  const int* dstA = eidx + E;

  float* ws = (float*)d_ws;
  float* ea_sum  = ws + 0;
  float* we_att  = ws + 64;
  float* al_self = ws + 1024;
  float* ws_att  = ws + 2048;
  size_t o = 8192;
  int* deg    = (int*)(ws + o); o += N;
  int* offs   = (int*)(ws + o); o += N + 1;
  int* cursor = (int*)(ws + o); o += N;
  int* eid    = (int*)(ws + o); o += E;
  int* srcp   = (int*)(ws + o); o += E;
  int* dstp   = (int*)(ws + o); o += E;
  int* posOf  = (int*)(ws + o); o += E;
  o = (o + 255) & ~(size_t)255;
  unsigned short* Bt  = (unsigned short*)(ws + o); o += (size_t)L*DD*HDIM/2;
  unsigned short* Bh  = (unsigned short*)(ws + o); o += 8*64*8/2;
  unsigned short* Wte = (unsigned short*)(ws + o); o += DD*DD/2;
  unsigned short* Bhd = (unsigned short*)(ws + o); o += 256*DD/2;
  unsigned short* xbf = (unsigned short*)(ws + o); o += (size_t)N*DD/2;
  unsigned short* hm_bf = (unsigned short*)(ws + o); o += (size_t)N*DD/2;
  float* al_s  = ws + o; o += (size_t)N*4;
  float* al_d  = ws + o; o += (size_t)N*4;
  unsigned short* eap = (unsigned short*)(ws + o); o += (size_t)E*EFEAT/2;
  float* abuf  = ws + o; o += (size_t)E*4;
  unsigned short* z = (unsigned short*)(ws + o); o += (size_t)Npad*HDIM/2;
  unsigned short* hbf  = hm_bf;
  unsigned short* pbuf = z;

  hipMemsetAsync(ea_sum, 0, EFEAT*sizeof(float), stream);
  hipMemsetAsync(deg, 0, (size_t)N*sizeof(int), stream);
  ea_sum4_kernel<<<1024, 256, 0, stream>>>(eattr, ea_sum, E);
  hist_kernel<<<(E + 255)/256, 256, 0, stream>>>(dstA, deg, E);
  scan_kernel<<<1, 1024, 0, stream>>>(deg, offs, N);
  hipMemcpyAsync(cursor, offs, (size_t)N*sizeof(int), hipMemcpyDeviceToDevice, stream);
  scatter_kernel<<<(E + 255)/256, 256, 0, stream>>>(dstA, srcA, cursor, eid, srcp, dstp,
                                                    posOf, E);
  eap_prep_kernel<<<(E*8 + 255)/256, 256, 0, stream>>>(eattr, eid, eap, E);
  fold_ws_kernel<<<(L*DD*8 + 3)/4, 256, 0, stream>>>(gatW, attS, attD, ws_att, L);
  fold_we_kernel<<<(L*EFEAT*NHEAD + 3)/4, 256, 0, stream>>>(gatWe, attE, we_att, L);
  fold_self_kernel<<<1, 64, 0, stream>>>(we_att, ea_sum, 1.0f/(float)E, al_self, L);
  bt_prep_kernel<<<(L*DD*HDIM + 255)/256, 256, 0, stream>>>(gatW, Bt, L*DD*HDIM);
  embwt_prep_kernel<<<(DD*DD + 255)/256, 256, 0, stream>>>(embW, Wte);
  w1ab_prep_kernel<<<(256*DD + 255)/256, 256, 0, stream>>>(hW1, Bhd);
  w1c_prep_kernel<<<(8*64*8 + 255)/256, 256, 0, stream>>>(hW1 + 2*DD*DD, Bh);
  bf16_conv_kernel<<<(N*DD/4 + 255)/256, 256, 0, stream>>>(x, xbf, N*DD/4);

  // embed + LN/FiLM/al (layer 0)
  gemm_fused_kernel<128,128><<<(N + 63)/64, 256, 0, stream>>>(
      xbf, Wte, embB, 1.0f, 0, 0, lnS, lnB, gamma, beta, ws_att,
      hm_bf, al_s, al_d, nullptr, N);

  for (int l = 0; l < L; l++){
    edge_logit_kernel<<<(E + 255)/256, 256, 0, stream>>>(eap, al_s, al_d, srcp, dstp,
        we_att + (size_t)l*EFEAT*NHEAD, abuf, E);
    aggregate3_kernel<<<N, 64, 0, stream>>>(hm_bf, abuf, al_s, al_d,
        al_self + (size_t)l*NHEAD, offs, srcp, z, N);
    if (l < L - 1){
      gemm_fused_kernel<512,128><<<(N + 63)/64, 256, 0, stream>>>(
          z, Bt + (size_t)l*DD*HDIM, gatB + (size_t)l*DD, 0.25f, 1, 0,
          lnS + (l+1)*DD, lnB + (l+1)*DD, gamma + (l+1)*DD, beta + (l+1)*DD,
          ws_att + (size_t)(l+1)*DD*8, hm_bf, al_s, al_d, nullptr, N);
    } else {
      gemm_fused_kernel<512,128><<<(N + 63)/64, 256, 0, stream>>>(
          z, Bt + (size_t)l*DD*HDIM, gatB + (size_t)l*DD, 0.25f, 1, 1,
          nullptr, nullptr, nullptr, nullptr, nullptr,
          nullptr, nullptr, nullptr, hbf, N);
    }
  }

  // head pre-projection: pbuf[N,256] = hbf @ [W1a|W1b] (+hB1 on cols<128)
  gemm_fused_kernel<128,256><<<(N + 63)/64, 256, 0, stream>>>(
      hbf, Bhd, hB1, 1.0f, 0, 1, nullptr, nullptr, nullptr, nullptr, nullptr,
      nullptr, nullptr, nullptr, pbuf, N);

  head_mfma_kernel<<<(E + 63)/64, 256, 0, stream>>>(eap, posOf, Bh, pbuf,
      hW2, hB2, srcA, dstA, out, E);
}

// Round 9
// 725.789 us; speedup vs baseline: 1.1769x; 1.1769x over previous
//
#include <hip/hip_runtime.h>

#define DD 128      // GNN_DIM == NODE_FEAT
#define HDIM 512    // H * D
#define EFEAT 32
#define NHEAD 4

typedef short s16x8 __attribute__((ext_vector_type(8)));
typedef float f32x4 __attribute__((ext_vector_type(4)));

__device__ __forceinline__ float lrelu(float x){ return x > 0.f ? x : 0.2f*x; }

__device__ __forceinline__ unsigned short f2bf(float f){
  unsigned u = __float_as_uint(f);
  unsigned r = (u + 0x7FFFu + ((u >> 16) & 1u)) >> 16;
  return (unsigned short)r;
}
__device__ __forceinline__ float bf2f(unsigned short u){
  return __uint_as_float(((unsigned)u) << 16);
}

__device__ __forceinline__ float waveReduceSum(float v){
  #pragma unroll
  for (int m = 1; m < 64; m <<= 1) v += __shfl_xor(v, m, 64);
  return v;
}
__device__ __forceinline__ float waveReduceMax(float v){
  #pragma unroll
  for (int m = 1; m < 64; m <<= 1) v = fmaxf(v, __shfl_xor(v, m, 64));
  return v;
}
__device__ __forceinline__ float quadReduceSum(float v){
  v += __shfl_xor(v, 1, 64); v += __shfl_xor(v, 2, 64);
  v += __shfl_xor(v, 4, 64); v += __shfl_xor(v, 8, 64);
  return v;
}

// ---------------- edge-attr column sums (float4, saturating grid) ----------------
__global__ __launch_bounds__(256) void ea_sum4_kernel(const float* __restrict__ ea,
                                                      float* __restrict__ ea_sum, int E){
  __shared__ float s[EFEAT];
  int t = threadIdx.x;
  if (t < EFEAT) s[t] = 0.f;
  __syncthreads();
  int nvec = E*8;
  float4 acc = make_float4(0.f, 0.f, 0.f, 0.f);
  for (int i = blockIdx.x*256 + t; i < nvec; i += gridDim.x*256){
    float4 v = *((const float4*)ea + i);
    acc.x += v.x; acc.y += v.y; acc.z += v.z; acc.w += v.w;
  }
  int cg = (t & 7)*4;
  atomicAdd(&s[cg + 0], acc.x); atomicAdd(&s[cg + 1], acc.y);
  atomicAdd(&s[cg + 2], acc.z); atomicAdd(&s[cg + 3], acc.w);
  __syncthreads();
  if (t < EFEAT) atomicAdd(&ea_sum[t], s[t]);
}

// ---------------- CSR build over dst ----------------
__global__ void hist_kernel(const int* __restrict__ dst, int* __restrict__ deg, int E){
  int e = blockIdx.x*blockDim.x + threadIdx.x;
  if (e < E) atomicAdd(&deg[dst[e]], 1);
}

__global__ void scan_kernel(const int* __restrict__ deg, int* __restrict__ offs, int N){
  __shared__ int s[1024];
  int t = threadIdx.x;
  int chunk = (N + 1023) >> 10;
  int b = t*chunk, e = min(b + chunk, N);
  int sum = 0;
  for (int i = b; i < e; i++) sum += deg[i];
  s[t] = sum;
  __syncthreads();
  for (int d = 1; d < 1024; d <<= 1){
    int x = (t >= d) ? s[t - d] : 0;
    __syncthreads();
    s[t] += x;
    __syncthreads();
  }
  int run = s[t] - sum;
  for (int i = b; i < e; i++){ offs[i] = run; run += deg[i]; }
  if (t == 1023) offs[N] = s[1023];
}

__global__ void scatter_kernel(const int* __restrict__ dst, const int* __restrict__ src,
                               int* __restrict__ cursor, int* __restrict__ eid,
                               int* __restrict__ srcp, int* __restrict__ dstp,
                               int* __restrict__ posOf, int E){
  int e = blockIdx.x*blockDim.x + threadIdx.x;
  if (e < E){
    int d = dst[e];
    int p = atomicAdd(&cursor[d], 1);
    eid[p] = e;
    srcp[p] = src[e];
    dstp[p] = d;
    posOf[e] = p;
  }
}

// ---------------- permute+convert edge attrs into CSR order (bf16, float4) ------------
__global__ void eap_prep_kernel(const float* __restrict__ ea, const int* __restrict__ eid,
                                unsigned short* __restrict__ eap, int E){
  int idx = blockIdx.x*blockDim.x + threadIdx.x;
  int p = idx >> 3, q = idx & 7;
  if (p >= E) return;
  float4 v = *((const float4*)(ea + (size_t)eid[p]*EFEAT) + q);
  ushort4 u = make_ushort4(f2bf(v.x), f2bf(v.y), f2bf(v.z), f2bf(v.w));
  *((ushort4*)(eap + (size_t)p*EFEAT) + q) = u;
}

// ---------------- fp32 -> bf16 convert (float4 -> ushort4) ----------------
__global__ void bf16_conv_kernel(const float* __restrict__ in,
                                 unsigned short* __restrict__ out, int nvec){
  int i = blockIdx.x*blockDim.x + threadIdx.x;
  if (i >= nvec) return;
  float4 v = *((const float4*)in + i);
  *((ushort4*)out + i) = make_ushort4(f2bf(v.x), f2bf(v.y), f2bf(v.z), f2bf(v.w));
}

// ---------------- parallel folds: wave per output ----------------
__global__ __launch_bounds__(256) void fold_ws_kernel(const float* __restrict__ gat_W,
    const float* __restrict__ att_src, const float* __restrict__ att_dst,
    float* __restrict__ ws_att, int L){
  int wave = threadIdx.x >> 6, lane = threadIdx.x & 63;
  int idx = blockIdx.x*4 + wave;
  if (idx >= L*DD*8) return;
  int j = idx & 7; int k = (idx >> 3) & 127; int l = idx >> 10;
  int h = j & 3;
  const float* att = (j < 4) ? att_src : att_dst;
  const float* av = att + (size_t)(l*NHEAD + h)*DD;
  const float* Wl = gat_W + (size_t)l*DD*HDIM + (size_t)k*HDIM + h*DD;
  float acc = Wl[lane]*av[lane] + Wl[lane + 64]*av[lane + 64];
  acc = waveReduceSum(acc);
  if (lane == 0) ws_att[idx] = acc;
}

__global__ __launch_bounds__(256) void fold_we_kernel(const float* __restrict__ gat_We,
    const float* __restrict__ att_edge, float* __restrict__ we_att, int L){
  int wave = threadIdx.x >> 6, lane = threadIdx.x & 63;
  int idx = blockIdx.x*4 + wave;
  if (idx >= L*EFEAT*NHEAD) return;
  int h = idx & 3; int f = (idx >> 2) & 31; int l = idx >> 7;
  const float* av = att_edge + (size_t)(l*NHEAD + h)*DD;
  const float* Wel = gat_We + (size_t)l*EFEAT*HDIM + (size_t)f*HDIM + h*DD;
  float acc = Wel[lane]*av[lane] + Wel[lane + 64]*av[lane + 64];
  acc = waveReduceSum(acc);
  if (lane == 0) we_att[idx] = acc;
}

__global__ void fold_self_kernel(const float* __restrict__ we_att,
    const float* __restrict__ ea_sum, float invE, float* __restrict__ al_self, int L){
  int t = threadIdx.x;
  if (t >= L*NHEAD) return;
  int h = t & 3; int l = t >> 2;
  float acc = 0.f;
  for (int f = 0; f < EFEAT; f++) acc += ea_sum[f]*invE * we_att[(l*EFEAT + f)*NHEAD + h];
  al_self[t] = acc;
}

// ---------------- transpose+convert gat_W to bf16 Bt[l][n=128][k=512] ----------------
__global__ void bt_prep_kernel(const float* __restrict__ gat_W,
                               unsigned short* __restrict__ Bt, int total){
  int i = blockIdx.x*blockDim.x + threadIdx.x;
  if (i >= total) return;
  int l = i >> 16; int rem = i & 65535;
  int d = rem >> 9; int kk = rem & 511;
  int k = kk & 127; int h = kk >> 7;
  Bt[i] = f2bf(gat_W[(size_t)l*DD*HDIM + (size_t)k*HDIM + h*DD + d]);
}

// ---------------- embW -> bf16 transposed [128][128] ----------------
__global__ void embwt_prep_kernel(const float* __restrict__ embW,
                                  unsigned short* __restrict__ Wt){
  int i = blockIdx.x*blockDim.x + threadIdx.x;
  if (i >= DD*DD) return;
  int n = i >> 7, k = i & 127;
  Wt[i] = f2bf(embW[(size_t)k*DD + n]);
}

// ---------------- [W1a | W1b] -> bf16 transposed [256][128] ----------------
__global__ void w1ab_prep_kernel(const float* __restrict__ hW1,
                                 unsigned short* __restrict__ Bhd){
  int i = blockIdx.x*blockDim.x + threadIdx.x;
  if (i >= 256*DD) return;
  int n = i >> 7, k = i & 127;
  float v = (n < 128) ? hW1[(size_t)k*DD + n] : hW1[(size_t)(128 + k)*DD + (n - 128)];
  Bhd[i] = f2bf(v);
}

// ---------------- W1c -> MFMA B-fragment layout: Bh[c][lane][j] ----------------
__global__ void w1c_prep_kernel(const float* __restrict__ W1c, unsigned short* __restrict__ Bh){
  int i = blockIdx.x*blockDim.x + threadIdx.x;
  if (i >= 8*64*8) return;
  int j = i & 7, lane = (i >> 3) & 63, c = i >> 9;
  int ln15 = lane & 15, quad = lane >> 4;
  int k = quad*8 + j, n = c*16 + ln15;
  Bh[i] = f2bf(W1c[(size_t)k*DD + n]);
}

// ---------------- unified MFMA GEMM + fused epilogues, LDS-staged B ----------------
// C_acc = scale * A[N,KD] @ Bt^T + bias   (Bt is [NOUT][KD], bf16)
// B staged per-128-K-chunk into LDS in MFMA fragment order: both the staging
// writes and the compute reads are base + lane*16 -> conflict-free; compute
// never touches global for B (kills the serial global-load latency chain of R8).
template<int KD, int NOUT>
__global__ __launch_bounds__(256) void gemm_fused_kernel(
    const unsigned short* __restrict__ A, const unsigned short* __restrict__ Bt,
    const float* __restrict__ bias, float scale, int relu, int mode,
    const float* __restrict__ ln_scale, const float* __restrict__ ln_bias,
    const float* __restrict__ gamma, const float* __restrict__ beta,
    const float* __restrict__ ws_att,
    unsigned short* __restrict__ hm_bf, float* __restrict__ al_s,
    float* __restrict__ al_d, unsigned short* __restrict__ outbf, int N){
  constexpr int NC = NOUT/16;        // 16-col blocks
  constexpr int NCH = KD/128;        // 128-wide K chunks
  __shared__ unsigned short Bs[4*NC*64*8];   // frag order: [(ks*NC+c)*64+lane][8]
  __shared__ float s_att[8*DD];              // transposed: s_att[j*DD + col]
  __shared__ float sP[4][DD];
  int t = threadIdx.x;
  if (mode == 0){
    for (int i = t; i < DD*8; i += 256){
      int col = i & 127, j = i >> 7;
      s_att[j*DD + col] = ws_att[col*8 + j];
    }
    for (int i = t; i < DD; i += 256){
      sP[0][i] = ln_scale[i]; sP[1][i] = ln_bias[i];
      sP[2][i] = gamma[i];    sP[3][i] = beta[i];
    }
  }
  int wave = t >> 6, lane = t & 63;
  int ln15 = lane & 15, quad = lane >> 4;
  int row0 = blockIdx.x*64 + wave*16;
  int arow = row0 + ln15;
  if (arow > N - 1) arow = N - 1;
  const unsigned short* aptr = A + (size_t)arow*KD;

  f32x4 acc[NC];
  #pragma unroll
  for (int c = 0; c < NC; c++) acc[c] = (f32x4)(0.f);

  for (int ch = 0; ch < NCH; ch++){
    __syncthreads();   // protect Bs from previous chunk's readers (and cover s_att/sP on ch 0)
    // stage chunk ch of B into LDS in fragment order: 256*NC frags of 16B
    #pragma unroll
    for (int i = 0; i < NC; i++){
      int g = i*256 + t;
      int gl = g & 63;
      int gc = (g >> 6) % NC;
      int gks = (g >> 6) / NC;
      const unsigned short* src = Bt + (size_t)(gc*16 + (gl & 15))*KD
                                  + ch*128 + gks*32 + (gl >> 4)*8;
      *(uint4*)&Bs[(size_t)g*8] = *(const uint4*)src;
    }
    __syncthreads();
    // a-fragments for this chunk (4 independent loads)
    s16x8 af[4];
    #pragma unroll
    for (int ks = 0; ks < 4; ks++)
      af[ks] = *(const s16x8*)(aptr + ch*128 + ks*32 + quad*8);
    #pragma unroll
    for (int ks = 0; ks < 4; ks++){
      #pragma unroll
      for (int c = 0; c < NC; c++){
        s16x8 b = *(const s16x8*)&Bs[(size_t)((ks*NC + c)*64 + lane)*8];
        acc[c] = __builtin_amdgcn_mfma_f32_16x16x32_bf16(af[ks], b, acc[c], 0, 0, 0);
      }
    }
  }

  float bv[NC];
  #pragma unroll
  for (int c = 0; c < NC; c++){
    if constexpr (NOUT == 256) bv[c] = (c < 8) ? bias[c*16 + ln15] : 0.f;
    else bv[c] = bias[c*16 + ln15];
  }

  #pragma unroll
  for (int r = 0; r < 4; r++){
    int row = row0 + quad*4 + r;
    bool valid = (row < N);
    float hv[NC];
    #pragma unroll
    for (int c = 0; c < NC; c++){
      float v = scale*acc[c][r] + bv[c];
      hv[c] = relu ? fmaxf(v, 0.f) : v;
    }
    if (mode == 1){
      if (valid){
        #pragma unroll
        for (int c = 0; c < NC; c++)
          outbf[(size_t)row*NOUT + c*16 + ln15] = f2bf(hv[c]);
      }
      continue;
    }
    if constexpr (NOUT == 128){
      float sum = 0.f;
      #pragma unroll
      for (int c = 0; c < NC; c++) sum += hv[c];
      sum = quadReduceSum(sum);
      float mu = sum * (1.f/128.f);
      float vs = 0.f;
      #pragma unroll
      for (int c = 0; c < NC; c++){ float d = hv[c] - mu; vs += d*d; }
      vs = quadReduceSum(vs);
      float rstd = rsqrtf(vs*(1.f/128.f) + 1e-5f);
      float m[NC];
      #pragma unroll
      for (int c = 0; c < NC; c++){
        int col = c*16 + ln15;
        float hn = (hv[c] - mu)*rstd*sP[0][col] + sP[1][col];
        m[c] = sP[2][col]*hn + sP[3][col];
        if (valid) hm_bf[(size_t)row*DD + col] = f2bf(m[c]);
      }
      float alv[8];
      #pragma unroll
      for (int j = 0; j < 8; j++){
        float a = 0.f;
        #pragma unroll
        for (int c = 0; c < NC; c++) a += m[c]*s_att[j*DD + c*16 + ln15];
        alv[j] = quadReduceSum(a);
      }
      if (ln15 == 0 && valid){
        *(float4*)&al_s[(size_t)row*4] = make_float4(alv[0], alv[1], alv[2], alv[3]);
        *(float4*)&al_d[(size_t)row*4] = make_float4(alv[4], alv[5], alv[6], alv[7]);
      }
    }
  }
}

// ---------------- edge-parallel attention logits in CSR order ----------------
__global__ __launch_bounds__(256) void edge_logit_kernel(
    const unsigned short* __restrict__ eap, const float* __restrict__ al_s,
    const float* __restrict__ al_d, const int* __restrict__ srcp,
    const int* __restrict__ dstp, const float* __restrict__ we_att,
    float* __restrict__ abuf, int E){
  __shared__ float4 swe[EFEAT];
  int t = threadIdx.x;
  if (t < EFEAT) swe[t] = *(const float4*)&we_att[t*4];
  __syncthreads();
  int p = blockIdx.x*256 + t;
  if (p >= E) return;
  int s = srcp[p], d = dstp[p];
  float4 as = *(const float4*)&al_s[(size_t)s*4];
  float4 ad = *(const float4*)&al_d[(size_t)d*4];
  float a0 = as.x + ad.x, a1 = as.y + ad.y, a2 = as.z + ad.z, a3 = as.w + ad.w;
  const uint4* ep = (const uint4*)(eap + (size_t)p*EFEAT);
  #pragma unroll
  for (int q = 0; q < 4; q++){
    uint4 u = ep[q];
    unsigned arr[4] = {u.x, u.y, u.z, u.w};
    #pragma unroll
    for (int j = 0; j < 4; j++){
      float x0 = bf2f((unsigned short)(arr[j] & 0xffff));
      float x1 = bf2f((unsigned short)(arr[j] >> 16));
      float4 w0 = swe[q*8 + j*2], w1 = swe[q*8 + j*2 + 1];
      a0 += x0*w0.x + x1*w1.x;
      a1 += x0*w0.y + x1*w1.y;
      a2 += x0*w0.z + x1*w1.z;
      a3 += x0*w0.w + x1*w1.w;
    }
  }
  *(float4*)&abuf[(size_t)p*4] = make_float4(lrelu(a0), lrelu(a1), lrelu(a2), lrelu(a3));
}

// ---------------- fused softmax + aggregation (block per node, 64 threads) ------------
__global__ __launch_bounds__(64) void aggregate3_kernel(
    const unsigned short* __restrict__ hm_bf, const float* __restrict__ abuf,
    const float* __restrict__ al_s, const float* __restrict__ al_d,
    const float* __restrict__ al_self4, const int* __restrict__ offs,
    const int* __restrict__ srcp, unsigned short* __restrict__ z, int N){
  int n = blockIdx.x, t = threadIdx.x;
  int beg = offs[n], end = offs[n + 1];
  float4 aslf = *(const float4*)al_self4;
  float4 asn = *(const float4*)&al_s[(size_t)n*4];
  float4 adn = *(const float4*)&al_d[(size_t)n*4];
  float s0 = lrelu(asn.x + adn.x + aslf.x);
  float s1 = lrelu(asn.y + adn.y + aslf.y);
  float s2 = lrelu(asn.z + adn.z + aslf.z);
  float s3 = lrelu(asn.w + adn.w + aslf.w);
  float m0 = s0, m1 = s1, m2 = s2, m3 = s3;
  for (int p = beg + t; p < end; p += 64){
    float4 a = *(const float4*)&abuf[(size_t)p*4];
    m0 = fmaxf(m0, a.x); m1 = fmaxf(m1, a.y);
    m2 = fmaxf(m2, a.z); m3 = fmaxf(m3, a.w);
  }
  m0 = waveReduceMax(m0); m1 = waveReduceMax(m1);
  m2 = waveReduceMax(m2); m3 = waveReduceMax(m3);
  float e0 = __expf(s0 - m0), e1 = __expf(s1 - m1);
  float e2 = __expf(s2 - m2), e3 = __expf(s3 - m3);
  ushort2 hv = *((const ushort2*)(hm_bf + (size_t)n*DD) + t);
  float h0 = bf2f(hv.x), h1 = bf2f(hv.y);
  float ac00 = e0*h0, ac01 = e0*h1;
  float ac10 = e1*h0, ac11 = e1*h1;
  float ac20 = e2*h0, ac21 = e2*h1;
  float ac30 = e3*h0, ac31 = e3*h1;
  float den0 = e0, den1 = e1, den2 = e2, den3 = e3;
  int p = beg;
  for (; p + 2 <= end; p += 2){
    int sA = srcp[p], sB = srcp[p + 1];
    float4 aA = *(const float4*)&abuf[(size_t)p*4];
    float4 aB = *(const float4*)&abuf[(size_t)(p + 1)*4];
    ushort2 vA = *((const ushort2*)(hm_bf + (size_t)sA*DD) + t);
    ushort2 vB = *((const ushort2*)(hm_bf + (size_t)sB*DD) + t);
    float wA0 = __expf(aA.x - m0), wA1 = __expf(aA.y - m1);
    float wA2 = __expf(aA.z - m2), wA3 = __expf(aA.w - m3);
    float wB0 = __expf(aB.x - m0), wB1 = __expf(aB.y - m1);
    float wB2 = __expf(aB.z - m2), wB3 = __expf(aB.w - m3);
    float vA0 = bf2f(vA.x), vA1 = bf2f(vA.y);
    float vB0 = bf2f(vB.x), vB1 = bf2f(vB.y);
    ac00 += wA0*vA0 + wB0*vB0; ac01 += wA0*vA1 + wB0*vB1;
    ac10 += wA1*vA0 + wB1*vB0; ac11 += wA1*vA1 + wB1*vB1;
    ac20 += wA2*vA0 + wB2*vB0; ac21 += wA2*vA1 + wB2*vB1;
    ac30 += wA3*vA0 + wB3*vB0; ac31 += wA3*vA1 + wB3*vB1;
    den0 += wA0 + wB0; den1 += wA1 + wB1;
    den2 += wA2 + wB2; den3 += wA3 + wB3;
  }
  if (p < end){
    int s = srcp[p];
    float4 a = *(const float4*)&abuf[(size_t)p*4];
    ushort2 v2 = *((const ushort2*)(hm_bf + (size_t)s*DD) + t);
    float w0 = __expf(a.x - m0), w1 = __expf(a.y - m1);
    float w2 = __expf(a.z - m2), w3 = __expf(a.w - m3);
    float v0 = bf2f(v2.x), v1 = bf2f(v2.y);
    ac00 += w0*v0; ac01 += w0*v1;
    ac10 += w1*v0; ac11 += w1*v1;
    ac20 += w2*v0; ac21 += w2*v1;
    ac30 += w3*v0; ac31 += w3*v1;
    den0 += w0; den1 += w1; den2 += w2; den3 += w3;
  }
  float r0 = 1.f/(den0 + 1e-16f), r1 = 1.f/(den1 + 1e-16f);
  float r2 = 1.f/(den2 + 1e-16f), r3 = 1.f/(den3 + 1e-16f);
  size_t zb = (size_t)n*HDIM;
  ushort2* zp = (ushort2*)(z + zb);
  zp[0*64 + t] = make_ushort2(f2bf(ac00*r0), f2bf(ac01*r0));
  zp[1*64 + t] = make_ushort2(f2bf(ac10*r1), f2bf(ac11*r1));
  zp[2*64 + t] = make_ushort2(f2bf(ac20*r2), f2bf(ac21*r2));
  zp[3*64 + t] = make_ushort2(f2bf(ac30*r3), f2bf(ac31*r3));
}

// ---------------- MFMA edge head: out[e] = relu(p[s]+p[d]+ea@W1c)@W2 + b2 ------------
__global__ __launch_bounds__(256) void head_mfma_kernel(
    const unsigned short* __restrict__ eap, const int* __restrict__ posOf,
    const unsigned short* __restrict__ Bh, const unsigned short* __restrict__ pbuf,
    const float* __restrict__ W2, const float* __restrict__ b2,
    const int* __restrict__ srcA, const int* __restrict__ dstA,
    float* __restrict__ out, int E){
  int t = threadIdx.x;
  int wave = t >> 6, lane = t & 63;
  int ln15 = lane & 15, quad = lane >> 4;
  int e0 = (blockIdx.x*4 + wave)*16;
  if (e0 >= E) return;
  int arow = e0 + ln15;
  if (arow > E - 1) arow = E - 1;
  int ap = posOf[arow];
  s16x8 a = *(const s16x8*)(eap + (size_t)ap*EFEAT + quad*8);
  f32x4 acc[8];
  #pragma unroll
  for (int c = 0; c < 8; c++){
    s16x8 b = *(const s16x8*)(Bh + ((size_t)c*64 + lane)*8);
    acc[c] = __builtin_amdgcn_mfma_f32_16x16x32_bf16(a, b, (f32x4)(0.f), 0, 0, 0);
  }
  float w2v[8];
  #pragma unroll
  for (int c = 0; c < 8; c++) w2v[c] = W2[c*16 + ln15];
  float res[4];
  #pragma unroll
  for (int r = 0; r < 4; r++){
    int e = e0 + quad*4 + r;
    int ec = (e < E) ? e : E - 1;
    int s = srcA[ec], d = dstA[ec];
    const unsigned short* ps = pbuf + (size_t)s*256 + ln15;
    const unsigned short* pd = pbuf + (size_t)d*256 + 128 + ln15;
    float sum = 0.f;
    #pragma unroll
    for (int c = 0; c < 8; c++){
      float q = acc[c][r] + bf2f(ps[c*16]) + bf2f(pd[c*16]);
      sum += fmaxf(q, 0.f) * w2v[c];
    }
    res[r] = sum;
  }
  #pragma unroll
  for (int r = 0; r < 4; r++){
    float v = res[r];
    v += __shfl_xor(v, 1, 64); v += __shfl_xor(v, 2, 64);
    v += __shfl_xor(v, 4, 64); v += __shfl_xor(v, 8, 64);
    res[r] = v;
  }
  if (ln15 == 0){
    float bb = b2[0];
    #pragma unroll
    for (int r = 0; r < 4; r++){
      int e = e0 + quad*4 + r;
      if (e < E) out[e] = res[r] + bb;
    }
  }
}

extern "C" void kernel_launch(void* const* d_in, const int* in_sizes, int n_in,
                              void* d_out, int out_size, void* d_ws, size_t ws_size,
                              hipStream_t stream){
  const float* x      = (const float*)d_in[0];
  const int*   eidx   = (const int*)d_in[1];
  const float* eattr  = (const float*)d_in[2];
  const float* gamma  = (const float*)d_in[3];
  const float* beta   = (const float*)d_in[4];
  const float* embW   = (const float*)d_in[5];
  const float* embB   = (const float*)d_in[6];
  const float* lnS    = (const float*)d_in[7];
  const float* lnB    = (const float*)d_in[8];
  const float* gatW   = (const float*)d_in[9];
  const float* attS   = (const float*)d_in[10];
  const float* attD   = (const float*)d_in[11];
  const float* gatWe  = (const float*)d_in[12];
  const float* attE   = (const float*)d_in[13];
  const float* gatB   = (const float*)d_in[14];
  const float* hW1    = (const float*)d_in[15];
  const float* hB1    = (const float*)d_in[16];
  const float* hW2    = (const float*)d_in[17];
  const float* hB2    = (const float*)d_in[18];
  float* out = (float*)d_out;

  int N = in_sizes[0] / DD;
  int E = in_sizes[1] / 2;
  int L = in_sizes[3] / DD;
  int Npad = (N + 63) & ~63;

  const int* srcA = eidx;
  const int* dstA = eidx + E;

  float* ws = (float*)d_ws;
  float* ea_sum  = ws + 0;
  float* we_att  = ws + 64;
  float* al_self = ws + 1024;
  float* ws_att  = ws + 2048;
  size_t o = 8192;
  int* deg    = (int*)(ws + o); o += N;
  int* offs   = (int*)(ws + o); o += N + 1;
  int* cursor = (int*)(ws + o); o += N;
  int* eid    = (int*)(ws + o); o += E;
  int* srcp   = (int*)(ws + o); o += E;
  int* dstp   = (int*)(ws + o); o += E;
  int* posOf  = (int*)(ws + o); o += E;
  o = (o + 255) & ~(size_t)255;
  unsigned short* Bt  = (unsigned short*)(ws + o); o += (size_t)L*DD*HDIM/2;
  unsigned short* Bh  = (unsigned short*)(ws + o); o += 8*64*8/2;
  unsigned short* Wte = (unsigned short*)(ws + o); o += DD*DD/2;
  unsigned short* Bhd = (unsigned short*)(ws + o); o += 256*DD/2;
  unsigned short* xbf = (unsigned short*)(ws + o); o += (size_t)N*DD/2;
  unsigned short* hm_bf = (unsigned short*)(ws + o); o += (size_t)N*DD/2;
  float* al_s  = ws + o; o += (size_t)N*4;
  float* al_d  = ws + o; o += (size_t)N*4;
  unsigned short* eap = (unsigned short*)(ws + o); o += (size_t)E*EFEAT/2;
  float* abuf  = ws + o; o += (size_t)E*4;
  unsigned short* z = (unsigned short*)(ws + o); o += (size_t)Npad*HDIM/2;
  unsigned short* hbf  = hm_bf;
  unsigned short* pbuf = z;

  hipMemsetAsync(ea_sum, 0, EFEAT*sizeof(float), stream);
  hipMemsetAsync(deg, 0, (size_t)N*sizeof(int), stream);
  ea_sum4_kernel<<<1024, 256, 0, stream>>>(eattr, ea_sum, E);
  hist_kernel<<<(E + 255)/256, 256, 0, stream>>>(dstA, deg, E);
  scan_kernel<<<1, 1024, 0, stream>>>(deg, offs, N);
  hipMemcpyAsync(cursor, offs, (size_t)N*sizeof(int), hipMemcpyDeviceToDevice, stream);
  scatter_kernel<<<(E + 255)/256, 256, 0, stream>>>(dstA, srcA, cursor, eid, srcp, dstp,
                                                    posOf, E);
  eap_prep_kernel<<<(E*8 + 255)/256, 256, 0, stream>>>(eattr, eid, eap, E);
  fold_ws_kernel<<<(L*DD*8 + 3)/4, 256, 0, stream>>>(gatW, attS, attD, ws_att, L);
  fold_we_kernel<<<(L*EFEAT*NHEAD + 3)/4, 256, 0, stream>>>(gatWe, attE, we_att, L);
  fold_self_kernel<<<1, 64, 0, stream>>>(we_att, ea_sum, 1.0f/(float)E, al_self, L);
  bt_prep_kernel<<<(L*DD*HDIM + 255)/256, 256, 0, stream>>>(gatW, Bt, L*DD*HDIM);
  embwt_prep_kernel<<<(DD*DD + 255)/256, 256, 0, stream>>>(embW, Wte);
  w1ab_prep_kernel<<<(256*DD + 255)/256, 256, 0, stream>>>(hW1, Bhd);
  w1c_prep_kernel<<<(8*64*8 + 255)/256, 256, 0, stream>>>(hW1 + 2*DD*DD, Bh);
  bf16_conv_kernel<<<(N*DD/4 + 255)/256, 256, 0, stream>>>(x, xbf, N*DD/4);

  // embed + LN/FiLM/al (layer 0)
  gemm_fused_kernel<128,128><<<(N + 63)/64, 256, 0, stream>>>(
      xbf, Wte, embB, 1.0f, 0, 0, lnS, lnB, gamma, beta, ws_att,
      hm_bf, al_s, al_d, nullptr, N);

  for (int l = 0; l < L; l++){
    edge_logit_kernel<<<(E + 255)/256, 256, 0, stream>>>(eap, al_s, al_d, srcp, dstp,
        we_att + (size_t)l*EFEAT*NHEAD, abuf, E);
    aggregate3_kernel<<<N, 64, 0, stream>>>(hm_bf, abuf, al_s, al_d,
        al_self + (size_t)l*NHEAD, offs, srcp, z, N);
    if (l < L - 1){
      gemm_fused_kernel<512,128><<<(N + 63)/64, 256, 0, stream>>>(
          z, Bt + (size_t)l*DD*HDIM, gatB + (size_t)l*DD, 0.25f, 1, 0,
          lnS + (l+1)*DD, lnB + (l+1)*DD, gamma + (l+1)*DD, beta + (l+1)*DD,
          ws_att + (size_t)(l+1)*DD*8, hm_bf, al_s, al_d, nullptr, N);
    } else {
      gemm_fused_kernel<512,128><<<(N + 63)/64, 256, 0, stream>>>(
          z, Bt + (size_t)l*DD*HDIM, gatB + (size_t)l*DD, 0.25f, 1, 1,
          nullptr, nullptr, nullptr, nullptr, nullptr,
          nullptr, nullptr, nullptr, hbf, N);
    }
  }

  // head pre-projection: pbuf[N,256] = hbf @ [W1a|W1b] (+hB1 on cols<128)
  gemm_fused_kernel<128,256><<<(N + 63)/64, 256, 0, stream>>>(
      hbf, Bhd, hB1, 1.0f, 0, 1, nullptr, nullptr, nullptr, nullptr, nullptr,
      nullptr, nullptr, nullptr, pbuf, N);

  head_mfma_kernel<<<(E + 63)/64, 256, 0, stream>>>(eap, posOf, Bh, pbuf,
      hW2, hB2, srcA, dstA, out, E);
}

// Round 10
// 674.468 us; speedup vs baseline: 1.2665x; 1.0761x over previous
//
#include <hip/hip_runtime.h>

#define DD 128      // GNN_DIM == NODE_FEAT
#define HDIM 512    // H * D
#define EFEAT 32
#define NHEAD 4

typedef short s16x8 __attribute__((ext_vector_type(8)));
typedef float f32x4 __attribute__((ext_vector_type(4)));

__device__ __forceinline__ float lrelu(float x){ return x > 0.f ? x : 0.2f*x; }

__device__ __forceinline__ unsigned short f2bf(float f){
  unsigned u = __float_as_uint(f);
  unsigned r = (u + 0x7FFFu + ((u >> 16) & 1u)) >> 16;
  return (unsigned short)r;
}
__device__ __forceinline__ float bf2f(unsigned short u){
  return __uint_as_float(((unsigned)u) << 16);
}

__device__ __forceinline__ float waveReduceSum(float v){
  #pragma unroll
  for (int m = 1; m < 64; m <<= 1) v += __shfl_xor(v, m, 64);
  return v;
}
__device__ __forceinline__ float quadReduceSum(float v){
  v += __shfl_xor(v, 1, 64); v += __shfl_xor(v, 2, 64);
  v += __shfl_xor(v, 4, 64); v += __shfl_xor(v, 8, 64);
  return v;
}

// ---------------- edge-attr column sums (float4, saturating grid) ----------------
__global__ __launch_bounds__(256) void ea_sum4_kernel(const float* __restrict__ ea,
                                                      float* __restrict__ ea_sum, int E){
  __shared__ float s[EFEAT];
  int t = threadIdx.x;
  if (t < EFEAT) s[t] = 0.f;
  __syncthreads();
  int nvec = E*8;
  float4 acc = make_float4(0.f, 0.f, 0.f, 0.f);
  for (int i = blockIdx.x*256 + t; i < nvec; i += gridDim.x*256){
    float4 v = *((const float4*)ea + i);
    acc.x += v.x; acc.y += v.y; acc.z += v.z; acc.w += v.w;
  }
  int cg = (t & 7)*4;
  atomicAdd(&s[cg + 0], acc.x); atomicAdd(&s[cg + 1], acc.y);
  atomicAdd(&s[cg + 2], acc.z); atomicAdd(&s[cg + 3], acc.w);
  __syncthreads();
  if (t < EFEAT) atomicAdd(&ea_sum[t], s[t]);
}

// ---------------- CSR build over dst ----------------
__global__ void hist_kernel(const int* __restrict__ dst, int* __restrict__ deg, int E){
  int e = blockIdx.x*blockDim.x + threadIdx.x;
  if (e < E) atomicAdd(&deg[dst[e]], 1);
}

__global__ void scan_kernel(const int* __restrict__ deg, int* __restrict__ offs, int N){
  __shared__ int s[1024];
  int t = threadIdx.x;
  int chunk = (N + 1023) >> 10;
  int b = t*chunk, e = min(b + chunk, N);
  int sum = 0;
  for (int i = b; i < e; i++) sum += deg[i];
  s[t] = sum;
  __syncthreads();
  for (int d = 1; d < 1024; d <<= 1){
    int x = (t >= d) ? s[t - d] : 0;
    __syncthreads();
    s[t] += x;
    __syncthreads();
  }
  int run = s[t] - sum;
  for (int i = b; i < e; i++){ offs[i] = run; run += deg[i]; }
  if (t == 1023) offs[N] = s[1023];
}

// one packed 8B random write per edge (1 cache line vs 3) + sequential posOf
__global__ void scatter_kernel(const int* __restrict__ dst, const int* __restrict__ src,
                               int* __restrict__ cursor, int2* __restrict__ sd,
                               int* __restrict__ posOf, int E){
  int e = blockIdx.x*blockDim.x + threadIdx.x;
  if (e < E){
    int d = dst[e];
    int p = atomicAdd(&cursor[d], 1);
    sd[p] = make_int2(src[e], d);
    posOf[e] = p;
  }
}

// ---------------- convert edge attrs, scatter into CSR order (bf16) ------------
__global__ void eap_prep_kernel(const float* __restrict__ ea, const int* __restrict__ posOf,
                                unsigned short* __restrict__ eap, int E){
  int idx = blockIdx.x*blockDim.x + threadIdx.x;
  int e = idx >> 3, q = idx & 7;
  if (e >= E) return;
  int p = posOf[e];
  float4 v = *((const float4*)(ea + (size_t)e*EFEAT) + q);
  ushort4 u = make_ushort4(f2bf(v.x), f2bf(v.y), f2bf(v.z), f2bf(v.w));
  *((ushort4*)(eap + (size_t)p*EFEAT) + q) = u;
}

// ---------------- fp32 -> bf16 convert (float4 -> ushort4) ----------------
__global__ void bf16_conv_kernel(const float* __restrict__ in,
                                 unsigned short* __restrict__ out, int nvec){
  int i = blockIdx.x*blockDim.x + threadIdx.x;
  if (i >= nvec) return;
  float4 v = *((const float4*)in + i);
  *((ushort4*)out + i) = make_ushort4(f2bf(v.x), f2bf(v.y), f2bf(v.z), f2bf(v.w));
}

// ---------------- parallel folds: wave per output ----------------
__global__ __launch_bounds__(256) void fold_ws_kernel(const float* __restrict__ gat_W,
    const float* __restrict__ att_src, const float* __restrict__ att_dst,
    float* __restrict__ ws_att, int L){
  int wave = threadIdx.x >> 6, lane = threadIdx.x & 63;
  int idx = blockIdx.x*4 + wave;
  if (idx >= L*DD*8) return;
  int j = idx & 7; int k = (idx >> 3) & 127; int l = idx >> 10;
  int h = j & 3;
  const float* att = (j < 4) ? att_src : att_dst;
  const float* av = att + (size_t)(l*NHEAD + h)*DD;
  const float* Wl = gat_W + (size_t)l*DD*HDIM + (size_t)k*HDIM + h*DD;
  float acc = Wl[lane]*av[lane] + Wl[lane + 64]*av[lane + 64];
  acc = waveReduceSum(acc);
  if (lane == 0) ws_att[idx] = acc;
}

__global__ __launch_bounds__(256) void fold_we_kernel(const float* __restrict__ gat_We,
    const float* __restrict__ att_edge, float* __restrict__ we_att, int L){
  int wave = threadIdx.x >> 6, lane = threadIdx.x & 63;
  int idx = blockIdx.x*4 + wave;
  if (idx >= L*EFEAT*NHEAD) return;
  int h = idx & 3; int f = (idx >> 2) & 31; int l = idx >> 7;
  const float* av = att_edge + (size_t)(l*NHEAD + h)*DD;
  const float* Wel = gat_We + (size_t)l*EFEAT*HDIM + (size_t)f*HDIM + h*DD;
  float acc = Wel[lane]*av[lane] + Wel[lane + 64]*av[lane + 64];
  acc = waveReduceSum(acc);
  if (lane == 0) we_att[idx] = acc;
}

__global__ void fold_self_kernel(const float* __restrict__ we_att,
    const float* __restrict__ ea_sum, float invE, float* __restrict__ al_self, int L){
  int t = threadIdx.x;
  if (t >= L*NHEAD) return;
  int h = t & 3; int l = t >> 2;
  float acc = 0.f;
  for (int f = 0; f < EFEAT; f++) acc += ea_sum[f]*invE * we_att[(l*EFEAT + f)*NHEAD + h];
  al_self[t] = acc;
}

// ---------------- gat_W -> bf16 Bt[l][d][h*128+k], LDS-tiled transpose ----------------
// For each (l,h): Bt block [d][k] = gat_W[l][k*512 + h*128 + d]  (128x128 transpose)
__global__ __launch_bounds__(256) void bt_prep_kernel(const float* __restrict__ gat_W,
                                                      unsigned short* __restrict__ Bt, int LH){
  __shared__ float tile[32][33];
  int blk = blockIdx.x;
  int lh = blk >> 4;            // which (l,h)
  if (lh >= LH) return;
  int tl = blk & 15;
  int k0 = (tl & 3)*32, d0 = (tl >> 2)*32;
  int l = lh >> 2, h = lh & 3;
  const float* in = gat_W + (size_t)l*DD*HDIM + h*DD;
  unsigned short* outp = Bt + (size_t)l*DD*HDIM + h*DD;
  int tx = threadIdx.x & 31, ty = threadIdx.x >> 5;   // 32 x 8
  #pragma unroll
  for (int i = 0; i < 4; i++){
    int k = k0 + ty + i*8;
    tile[ty + i*8][tx] = in[(size_t)k*HDIM + d0 + tx];
  }
  __syncthreads();
  #pragma unroll
  for (int i = 0; i < 4; i++){
    int d = d0 + ty + i*8;
    outp[(size_t)d*HDIM + k0 + tx] = f2bf(tile[tx][ty + i*8]);
  }
}

// ---------------- embW -> bf16 transposed [128][128] ----------------
__global__ void embwt_prep_kernel(const float* __restrict__ embW,
                                  unsigned short* __restrict__ Wt){
  int i = blockIdx.x*blockDim.x + threadIdx.x;
  if (i >= DD*DD) return;
  int n = i >> 7, k = i & 127;
  Wt[i] = f2bf(embW[(size_t)k*DD + n]);
}

// ---------------- [W1a | W1b] -> bf16 transposed [256][128] ----------------
__global__ void w1ab_prep_kernel(const float* __restrict__ hW1,
                                 unsigned short* __restrict__ Bhd){
  int i = blockIdx.x*blockDim.x + threadIdx.x;
  if (i >= 256*DD) return;
  int n = i >> 7, k = i & 127;
  float v = (n < 128) ? hW1[(size_t)k*DD + n] : hW1[(size_t)(128 + k)*DD + (n - 128)];
  Bhd[i] = f2bf(v);
}

// ---------------- W1c -> MFMA B-fragment layout: Bh[c][lane][j] ----------------
__global__ void w1c_prep_kernel(const float* __restrict__ W1c, unsigned short* __restrict__ Bh){
  int i = blockIdx.x*blockDim.x + threadIdx.x;
  if (i >= 8*64*8) return;
  int j = i & 7, lane = (i >> 3) & 63, c = i >> 9;
  int ln15 = lane & 15, quad = lane >> 4;
  int k = quad*8 + j, n = c*16 + ln15;
  Bh[i] = f2bf(W1c[(size_t)k*DD + n]);
}

// ---------------- unified MFMA GEMM + fused epilogues, LDS-staged B ----------------
template<int KD, int NOUT>
__global__ __launch_bounds__(256) void gemm_fused_kernel(
    const unsigned short* __restrict__ A, const unsigned short* __restrict__ Bt,
    const float* __restrict__ bias, float scale, int relu, int mode,
    const float* __restrict__ ln_scale, const float* __restrict__ ln_bias,
    const float* __restrict__ gamma, const float* __restrict__ beta,
    const float* __restrict__ ws_att,
    unsigned short* __restrict__ hm_bf, float* __restrict__ al_s,
    float* __restrict__ al_d, unsigned short* __restrict__ outbf, int N){
  constexpr int NC = NOUT/16;
  constexpr int NCH = KD/128;
  __shared__ unsigned short Bs[4*NC*64*8];
  __shared__ float s_att[8*DD];
  __shared__ float sP[4][DD];
  int t = threadIdx.x;
  if (mode == 0){
    for (int i = t; i < DD*8; i += 256){
      int col = i & 127, j = i >> 7;
      s_att[j*DD + col] = ws_att[col*8 + j];
    }
    for (int i = t; i < DD; i += 256){
      sP[0][i] = ln_scale[i]; sP[1][i] = ln_bias[i];
      sP[2][i] = gamma[i];    sP[3][i] = beta[i];
    }
  }
  int wave = t >> 6, lane = t & 63;
  int ln15 = lane & 15, quad = lane >> 4;
  int row0 = blockIdx.x*64 + wave*16;
  int arow = row0 + ln15;
  if (arow > N - 1) arow = N - 1;
  const unsigned short* aptr = A + (size_t)arow*KD;

  f32x4 acc[NC];
  #pragma unroll
  for (int c = 0; c < NC; c++) acc[c] = (f32x4)(0.f);

  for (int ch = 0; ch < NCH; ch++){
    __syncthreads();
    #pragma unroll
    for (int i = 0; i < NC; i++){
      int g = i*256 + t;
      int gl = g & 63;
      int gc = (g >> 6) % NC;
      int gks = (g >> 6) / NC;
      const unsigned short* src = Bt + (size_t)(gc*16 + (gl & 15))*KD
                                  + ch*128 + gks*32 + (gl >> 4)*8;
      *(uint4*)&Bs[(size_t)g*8] = *(const uint4*)src;
    }
    __syncthreads();
    s16x8 af[4];
    #pragma unroll
    for (int ks = 0; ks < 4; ks++)
      af[ks] = *(const s16x8*)(aptr + ch*128 + ks*32 + quad*8);
    #pragma unroll
    for (int ks = 0; ks < 4; ks++){
      #pragma unroll
      for (int c = 0; c < NC; c++){
        s16x8 b = *(const s16x8*)&Bs[(size_t)((ks*NC + c)*64 + lane)*8];
        acc[c] = __builtin_amdgcn_mfma_f32_16x16x32_bf16(af[ks], b, acc[c], 0, 0, 0);
      }
    }
  }

  float bv[NC];
  #pragma unroll
  for (int c = 0; c < NC; c++){
    if constexpr (NOUT == 256) bv[c] = (c < 8) ? bias[c*16 + ln15] : 0.f;
    else bv[c] = bias[c*16 + ln15];
  }

  #pragma unroll
  for (int r = 0; r < 4; r++){
    int row = row0 + quad*4 + r;
    bool valid = (row < N);
    float hv[NC];
    #pragma unroll
    for (int c = 0; c < NC; c++){
      float v = scale*acc[c][r] + bv[c];
      hv[c] = relu ? fmaxf(v, 0.f) : v;
    }
    if (mode == 1){
      if (valid){
        #pragma unroll
        for (int c = 0; c < NC; c++)
          outbf[(size_t)row*NOUT + c*16 + ln15] = f2bf(hv[c]);
      }
      continue;
    }
    if constexpr (NOUT == 128){
      float sum = 0.f;
      #pragma unroll
      for (int c = 0; c < NC; c++) sum += hv[c];
      sum = quadReduceSum(sum);
      float mu = sum * (1.f/128.f);
      float vs = 0.f;
      #pragma unroll
      for (int c = 0; c < NC; c++){ float d = hv[c] - mu; vs += d*d; }
      vs = quadReduceSum(vs);
      float rstd = rsqrtf(vs*(1.f/128.f) + 1e-5f);
      float m[NC];
      #pragma unroll
      for (int c = 0; c < NC; c++){
        int col = c*16 + ln15;
        float hn = (hv[c] - mu)*rstd*sP[0][col] + sP[1][col];
        m[c] = sP[2][col]*hn + sP[3][col];
        if (valid) hm_bf[(size_t)row*DD + col] = f2bf(m[c]);
      }
      float alv[8];
      #pragma unroll
      for (int j = 0; j < 8; j++){
        float a = 0.f;
        #pragma unroll
        for (int c = 0; c < NC; c++) a += m[c]*s_att[j*DD + c*16 + ln15];
        alv[j] = quadReduceSum(a);
      }
      if (ln15 == 0 && valid){
        *(float4*)&al_s[(size_t)row*4] = make_float4(alv[0], alv[1], alv[2], alv[3]);
        *(float4*)&al_d[(size_t)row*4] = make_float4(alv[4], alv[5], alv[6], alv[7]);
      }
    }
  }
}

// ---------------- edge-parallel softmax weights in CSR order (no max shift) ------------
// softmax is shift-invariant; logits are O(few units) (0.05-scale weights), exp is fp32-safe
__global__ __launch_bounds__(256) void edge_logit_kernel(
    const unsigned short* __restrict__ eap, const float* __restrict__ al_s,
    const float* __restrict__ al_d, const int2* __restrict__ sd,
    const float* __restrict__ we_att, float* __restrict__ wbuf, int E){
  __shared__ float4 swe[EFEAT];
  int t = threadIdx.x;
  if (t < EFEAT) swe[t] = *(const float4*)&we_att[t*4];
  __syncthreads();
  int p = blockIdx.x*256 + t;
  if (p >= E) return;
  int2 e2 = sd[p];
  float4 as = *(const float4*)&al_s[(size_t)e2.x*4];
  float4 ad = *(const float4*)&al_d[(size_t)e2.y*4];
  float a0 = as.x + ad.x, a1 = as.y + ad.y, a2 = as.z + ad.z, a3 = as.w + ad.w;
  const uint4* ep = (const uint4*)(eap + (size_t)p*EFEAT);
  #pragma unroll
  for (int q = 0; q < 4; q++){
    uint4 u = ep[q];
    unsigned arr[4] = {u.x, u.y, u.z, u.w};
    #pragma unroll
    for (int j = 0; j < 4; j++){
      float x0 = bf2f((unsigned short)(arr[j] & 0xffff));
      float x1 = bf2f((unsigned short)(arr[j] >> 16));
      float4 w0 = swe[q*8 + j*2], w1 = swe[q*8 + j*2 + 1];
      a0 += x0*w0.x + x1*w1.x;
      a1 += x0*w0.y + x1*w1.y;
      a2 += x0*w0.z + x1*w1.z;
      a3 += x0*w0.w + x1*w1.w;
    }
  }
  *(float4*)&wbuf[(size_t)p*4] = make_float4(__expf(lrelu(a0)), __expf(lrelu(a1)),
                                             __expf(lrelu(a2)), __expf(lrelu(a3)));
}

// ---------------- single-pass weighted aggregation (block per node, 64 threads) --------
__global__ __launch_bounds__(64) void aggregate3_kernel(
    const unsigned short* __restrict__ hm_bf, const float* __restrict__ wbuf,
    const float* __restrict__ al_s, const float* __restrict__ al_d,
    const float* __restrict__ al_self4, const int* __restrict__ offs,
    const int2* __restrict__ sd, unsigned short* __restrict__ z, int N){
  int n = blockIdx.x, t = threadIdx.x;
  int beg = offs[n], end = offs[n + 1];
  float4 aslf = *(const float4*)al_self4;
  float4 asn = *(const float4*)&al_s[(size_t)n*4];
  float4 adn = *(const float4*)&al_d[(size_t)n*4];
  float e0 = __expf(lrelu(asn.x + adn.x + aslf.x));
  float e1 = __expf(lrelu(asn.y + adn.y + aslf.y));
  float e2 = __expf(lrelu(asn.z + adn.z + aslf.z));
  float e3 = __expf(lrelu(asn.w + adn.w + aslf.w));
  ushort2 hv = *((const ushort2*)(hm_bf + (size_t)n*DD) + t);
  float h0 = bf2f(hv.x), h1 = bf2f(hv.y);
  float ac00 = e0*h0, ac01 = e0*h1;
  float ac10 = e1*h0, ac11 = e1*h1;
  float ac20 = e2*h0, ac21 = e2*h1;
  float ac30 = e3*h0, ac31 = e3*h1;
  float den0 = e0, den1 = e1, den2 = e2, den3 = e3;
  int p = beg;
  for (; p + 2 <= end; p += 2){
    int sA = sd[p].x, sB = sd[p + 1].x;
    float4 wA = *(const float4*)&wbuf[(size_t)p*4];
    float4 wB = *(const float4*)&wbuf[(size_t)(p + 1)*4];
    ushort2 vA = *((const ushort2*)(hm_bf + (size_t)sA*DD) + t);
    ushort2 vB = *((const ushort2*)(hm_bf + (size_t)sB*DD) + t);
    float vA0 = bf2f(vA.x), vA1 = bf2f(vA.y);
    float vB0 = bf2f(vB.x), vB1 = bf2f(vB.y);
    ac00 += wA.x*vA0 + wB.x*vB0; ac01 += wA.x*vA1 + wB.x*vB1;
    ac10 += wA.y*vA0 + wB.y*vB0; ac11 += wA.y*vA1 + wB.y*vB1;
    ac20 += wA.z*vA0 + wB.z*vB0; ac21 += wA.z*vA1 + wB.z*vB1;
    ac30 += wA.w*vA0 + wB.w*vB0; ac31 += wA.w*vA1 + wB.w*vB1;
    den0 += wA.x + wB.x; den1 += wA.y + wB.y;
    den2 += wA.z + wB.z; den3 += wA.w + wB.w;
  }
  if (p < end){
    int s = sd[p].x;
    float4 w = *(const float4*)&wbuf[(size_t)p*4];
    ushort2 v2 = *((const ushort2*)(hm_bf + (size_t)s*DD) + t);
    float v0 = bf2f(v2.x), v1 = bf2f(v2.y);
    ac00 += w.x*v0; ac01 += w.x*v1;
    ac10 += w.y*v0; ac11 += w.y*v1;
    ac20 += w.z*v0; ac21 += w.z*v1;
    ac30 += w.w*v0; ac31 += w.w*v1;
    den0 += w.x; den1 += w.y; den2 += w.z; den3 += w.w;
  }
  float r0 = 1.f/(den0 + 1e-16f), r1 = 1.f/(den1 + 1e-16f);
  float r2 = 1.f/(den2 + 1e-16f), r3 = 1.f/(den3 + 1e-16f);
  size_t zb = (size_t)n*HDIM;
  ushort2* zp = (ushort2*)(z + zb);
  zp[0*64 + t] = make_ushort2(f2bf(ac00*r0), f2bf(ac01*r0));
  zp[1*64 + t] = make_ushort2(f2bf(ac10*r1), f2bf(ac11*r1));
  zp[2*64 + t] = make_ushort2(f2bf(ac20*r2), f2bf(ac21*r2));
  zp[3*64 + t] = make_ushort2(f2bf(ac30*r3), f2bf(ac31*r3));
}

// ---------------- MFMA edge head: out[e] = relu(p[s]+p[d]+ea@W1c)@W2 + b2 ------------
__global__ __launch_bounds__(256) void head_mfma_kernel(
    const unsigned short* __restrict__ eap, const int* __restrict__ posOf,
    const unsigned short* __restrict__ Bh, const unsigned short* __restrict__ pbuf,
    const float* __restrict__ W2, const float* __restrict__ b2,
    const int* __restrict__ srcA, const int* __restrict__ dstA,
    float* __restrict__ out, int E){
  int t = threadIdx.x;
  int wave = t >> 6, lane = t & 63;
  int ln15 = lane & 15, quad = lane >> 4;
  int e0 = (blockIdx.x*4 + wave)*16;
  if (e0 >= E) return;
  int arow = e0 + ln15;
  if (arow > E - 1) arow = E - 1;
  int ap = posOf[arow];
  s16x8 a = *(const s16x8*)(eap + (size_t)ap*EFEAT + quad*8);
  f32x4 acc[8];
  #pragma unroll
  for (int c = 0; c < 8; c++){
    s16x8 b = *(const s16x8*)(Bh + ((size_t)c*64 + lane)*8);
    acc[c] = __builtin_amdgcn_mfma_f32_16x16x32_bf16(a, b, (f32x4)(0.f), 0, 0, 0);
  }
  float w2v[8];
  #pragma unroll
  for (int c = 0; c < 8; c++) w2v[c] = W2[c*16 + ln15];
  float res[4];
  #pragma unroll
  for (int r = 0; r < 4; r++){
    int e = e0 + quad*4 + r;
    int ec = (e < E) ? e : E - 1;
    int s = srcA[ec], d = dstA[ec];
    const unsigned short* ps = pbuf + (size_t)s*256 + ln15;
    const unsigned short* pd = pbuf + (size_t)d*256 + 128 + ln15;
    float sum = 0.f;
    #pragma unroll
    for (int c = 0; c < 8; c++){
      float q = acc[c][r] + bf2f(ps[c*16]) + bf2f(pd[c*16]);
      sum += fmaxf(q, 0.f) * w2v[c];
    }
    res[r] = sum;
  }
  #pragma unroll
  for (int r = 0; r < 4; r++){
    float v = res[r];
    v += __shfl_xor(v, 1, 64); v += __shfl_xor(v, 2, 64);
    v += __shfl_xor(v, 4, 64); v += __shfl_xor(v, 8, 64);
    res[r] = v;
  }
  if (ln15 == 0){
    float bb = b2[0];
    #pragma unroll
    for (int r = 0; r < 4; r++){
      int e = e0 + quad*4 + r;
      if (e < E) out[e] = res[r] + bb;
    }
  }
}

extern "C" void kernel_launch(void* const* d_in, const int* in_sizes, int n_in,
                              void* d_out, int out_size, void* d_ws, size_t ws_size,
                              hipStream_t stream){
  const float* x      = (const float*)d_in[0];
  const int*   eidx   = (const int*)d_in[1];
  const float* eattr  = (const float*)d_in[2];
  const float* gamma  = (const float*)d_in[3];
  const float* beta   = (const float*)d_in[4];
  const float* embW   = (const float*)d_in[5];
  const float* embB   = (const float*)d_in[6];
  const float* lnS    = (const float*)d_in[7];
  const float* lnB    = (const float*)d_in[8];
  const float* gatW   = (const float*)d_in[9];
  const float* attS   = (const float*)d_in[10];
  const float* attD   = (const float*)d_in[11];
  const float* gatWe  = (const float*)d_in[12];
  const float* attE   = (const float*)d_in[13];
  const float* gatB   = (const float*)d_in[14];
  const float* hW1    = (const float*)d_in[15];
  const float* hB1    = (const float*)d_in[16];
  const float* hW2    = (const float*)d_in[17];
  const float* hB2    = (const float*)d_in[18];
  float* out = (float*)d_out;

  int N = in_sizes[0] / DD;
  int E = in_sizes[1] / 2;
  int L = in_sizes[3] / DD;
  int Npad = (N + 63) & ~63;

  const int* srcA = eidx;
  const int* dstA = eidx + E;

  float* ws = (float*)d_ws;
  float* ea_sum  = ws + 0;
  float* we_att  = ws + 64;
  float* al_self = ws + 1024;
  float* ws_att  = ws + 2048;
  size_t o = 8192;
  int* deg    = (int*)(ws + o); o += N;
  int* offs   = (int*)(ws + o); o += N + 1;
  int* cursor = (int*)(ws + o); o += N;
  o = (o + 1) & ~(size_t)1;
  int2* sd    = (int2*)(ws + o); o += (size_t)E*2;
  int* posOf  = (int*)(ws + o); o += E;
  o = (o + 255) & ~(size_t)255;
  unsigned short* Bt  = (unsigned short*)(ws + o); o += (size_t)L*DD*HDIM/2;
  unsigned short* Bh  = (unsigned short*)(ws + o); o += 8*64*8/2;
  unsigned short* Wte = (unsigned short*)(ws + o); o += DD*DD/2;
  unsigned short* Bhd = (unsigned short*)(ws + o); o += 256*DD/2;
  unsigned short* xbf = (unsigned short*)(ws + o); o += (size_t)N*DD/2;
  unsigned short* hm_bf = (unsigned short*)(ws + o); o += (size_t)N*DD/2;
  float* al_s  = ws + o; o += (size_t)N*4;
  float* al_d  = ws + o; o += (size_t)N*4;
  unsigned short* eap = (unsigned short*)(ws + o); o += (size_t)E*EFEAT/2;
  float* wbuf  = ws + o; o += (size_t)E*4;
  unsigned short* z = (unsigned short*)(ws + o); o += (size_t)Npad*HDIM/2;
  unsigned short* hbf  = hm_bf;
  unsigned short* pbuf = z;

  hipMemsetAsync(ea_sum, 0, EFEAT*sizeof(float), stream);
  hipMemsetAsync(deg, 0, (size_t)N*sizeof(int), stream);
  ea_sum4_kernel<<<1024, 256, 0, stream>>>(eattr, ea_sum, E);
  hist_kernel<<<(E + 255)/256, 256, 0, stream>>>(dstA, deg, E);
  scan_kernel<<<1, 1024, 0, stream>>>(deg, offs, N);
  hipMemcpyAsync(cursor, offs, (size_t)N*sizeof(int), hipMemcpyDeviceToDevice, stream);
  scatter_kernel<<<(E + 255)/256, 256, 0, stream>>>(dstA, srcA, cursor, sd, posOf, E);
  eap_prep_kernel<<<(E*8 + 255)/256, 256, 0, stream>>>(eattr, posOf, eap, E);
  fold_ws_kernel<<<(L*DD*8 + 3)/4, 256, 0, stream>>>(gatW, attS, attD, ws_att, L);
  fold_we_kernel<<<(L*EFEAT*NHEAD + 3)/4, 256, 0, stream>>>(gatWe, attE, we_att, L);
  fold_self_kernel<<<1, 64, 0, stream>>>(we_att, ea_sum, 1.0f/(float)E, al_self, L);
  bt_prep_kernel<<<L*NHEAD*16, 256, 0, stream>>>(gatW, Bt, L*NHEAD);
  embwt_prep_kernel<<<(DD*DD + 255)/256, 256, 0, stream>>>(embW, Wte);
  w1ab_prep_kernel<<<(256*DD + 255)/256, 256, 0, stream>>>(hW1, Bhd);
  w1c_prep_kernel<<<(8*64*8 + 255)/256, 256, 0, stream>>>(hW1 + 2*DD*DD, Bh);
  bf16_conv_kernel<<<(N*DD/4 + 255)/256, 256, 0, stream>>>(x, xbf, N*DD/4);

  // embed + LN/FiLM/al (layer 0)
  gemm_fused_kernel<128,128><<<(N + 63)/64, 256, 0, stream>>>(
      xbf, Wte, embB, 1.0f, 0, 0, lnS, lnB, gamma, beta, ws_att,
      hm_bf, al_s, al_d, nullptr, N);

  for (int l = 0; l < L; l++){
    edge_logit_kernel<<<(E + 255)/256, 256, 0, stream>>>(eap, al_s, al_d, sd,
        we_att + (size_t)l*EFEAT*NHEAD, wbuf, E);
    aggregate3_kernel<<<N, 64, 0, stream>>>(hm_bf, wbuf, al_s, al_d,
        al_self + (size_t)l*NHEAD, offs, sd, z, N);
    if (l < L - 1){
      gemm_fused_kernel<512,128><<<(N + 63)/64, 256, 0, stream>>>(
          z, Bt + (size_t)l*DD*HDIM, gatB + (size_t)l*DD, 0.25f, 1, 0,
          lnS + (l+1)*DD, lnB + (l+1)*DD, gamma + (l+1)*DD, beta + (l+1)*DD,
          ws_att + (size_t)(l+1)*DD*8, hm_bf, al_s, al_d, nullptr, N);
    } else {
      gemm_fused_kernel<512,128><<<(N + 63)/64, 256, 0, stream>>>(
          z, Bt + (size_t)l*DD*HDIM, gatB + (size_t)l*DD, 0.25f, 1, 1,
          nullptr, nullptr, nullptr, nullptr, nullptr,
          nullptr, nullptr, nullptr, hbf, N);
    }
  }

  // head pre-projection: pbuf[N,256] = hbf @ [W1a|W1b] (+hB1 on cols<128)
  gemm_fused_kernel<128,256><<<(N + 63)/64, 256, 0, stream>>>(
      hbf, Bhd, hB1, 1.0f, 0, 1, nullptr, nullptr, nullptr, nullptr, nullptr,
      nullptr, nullptr, nullptr, pbuf, N);

  head_mfma_kernel<<<(E + 63)/64, 256, 0, stream>>>(eap, posOf, Bh, pbuf,
      hW2, hB2, srcA, dstA, out, E);
}

// Round 11
// 667.618 us; speedup vs baseline: 1.2795x; 1.0103x over previous
//
#include <hip/hip_runtime.h>

#define DD 128      // GNN_DIM == NODE_FEAT
#define HDIM 512    // H * D
#define EFEAT 32
#define NHEAD 4

typedef short s16x8 __attribute__((ext_vector_type(8)));
typedef float f32x4 __attribute__((ext_vector_type(4)));

__device__ __forceinline__ float lrelu(float x){ return x > 0.f ? x : 0.2f*x; }

__device__ __forceinline__ unsigned short f2bf(float f){
  unsigned u = __float_as_uint(f);
  unsigned r = (u + 0x7FFFu + ((u >> 16) & 1u)) >> 16;
  return (unsigned short)r;
}
__device__ __forceinline__ float bf2f(unsigned short u){
  return __uint_as_float(((unsigned)u) << 16);
}

__device__ __forceinline__ float waveReduceSum(float v){
  #pragma unroll
  for (int m = 1; m < 64; m <<= 1) v += __shfl_xor(v, m, 64);
  return v;
}
__device__ __forceinline__ float quadReduceSum(float v){
  v += __shfl_xor(v, 1, 64); v += __shfl_xor(v, 2, 64);
  v += __shfl_xor(v, 4, 64); v += __shfl_xor(v, 8, 64);
  return v;
}

// ---------------- edge-attr column sums (float4, saturating grid) ----------------
__global__ __launch_bounds__(256) void ea_sum4_kernel(const float* __restrict__ ea,
                                                      float* __restrict__ ea_sum, int E){
  __shared__ float s[EFEAT];
  int t = threadIdx.x;
  if (t < EFEAT) s[t] = 0.f;
  __syncthreads();
  int nvec = E*8;
  float4 acc = make_float4(0.f, 0.f, 0.f, 0.f);
  for (int i = blockIdx.x*256 + t; i < nvec; i += gridDim.x*256){
    float4 v = *((const float4*)ea + i);
    acc.x += v.x; acc.y += v.y; acc.z += v.z; acc.w += v.w;
  }
  int cg = (t & 7)*4;
  atomicAdd(&s[cg + 0], acc.x); atomicAdd(&s[cg + 1], acc.y);
  atomicAdd(&s[cg + 2], acc.z); atomicAdd(&s[cg + 3], acc.w);
  __syncthreads();
  if (t < EFEAT) atomicAdd(&ea_sum[t], s[t]);
}

// ---------------- CSR build over dst ----------------
__global__ void hist_kernel(const int* __restrict__ dst, int* __restrict__ deg, int E){
  int e = blockIdx.x*blockDim.x + threadIdx.x;
  if (e < E) atomicAdd(&deg[dst[e]], 1);
}

__global__ void scan_kernel(const int* __restrict__ deg, int* __restrict__ offs, int N){
  __shared__ int s[1024];
  int t = threadIdx.x;
  int chunk = (N + 1023) >> 10;
  int b = t*chunk, e = min(b + chunk, N);
  int sum = 0;
  for (int i = b; i < e; i++) sum += deg[i];
  s[t] = sum;
  __syncthreads();
  for (int d = 1; d < 1024; d <<= 1){
    int x = (t >= d) ? s[t - d] : 0;
    __syncthreads();
    s[t] += x;
    __syncthreads();
  }
  int run = s[t] - sum;
  for (int i = b; i < e; i++){ offs[i] = run; run += deg[i]; }
  if (t == 1023) offs[N] = s[1023];
}

__global__ void scatter_kernel(const int* __restrict__ dst, const int* __restrict__ src,
                               int* __restrict__ cursor, int2* __restrict__ sd,
                               int* __restrict__ posOf, int E){
  int e = blockIdx.x*blockDim.x + threadIdx.x;
  if (e < E){
    int d = dst[e];
    int p = atomicAdd(&cursor[d], 1);
    sd[p] = make_int2(src[e], d);
    posOf[e] = p;
  }
}

// ---------------- convert edge attrs, scatter into CSR order (bf16) ------------
__global__ void eap_prep_kernel(const float* __restrict__ ea, const int* __restrict__ posOf,
                                unsigned short* __restrict__ eap, int E){
  int idx = blockIdx.x*blockDim.x + threadIdx.x;
  int e = idx >> 3, q = idx & 7;
  if (e >= E) return;
  int p = posOf[e];
  float4 v = *((const float4*)(ea + (size_t)e*EFEAT) + q);
  ushort4 u = make_ushort4(f2bf(v.x), f2bf(v.y), f2bf(v.z), f2bf(v.w));
  *((ushort4*)(eap + (size_t)p*EFEAT) + q) = u;
}

// ---------------- fp32 -> bf16 convert (float4 -> ushort4) ----------------
__global__ void bf16_conv_kernel(const float* __restrict__ in,
                                 unsigned short* __restrict__ out, int nvec){
  int i = blockIdx.x*blockDim.x + threadIdx.x;
  if (i >= nvec) return;
  float4 v = *((const float4*)in + i);
  *((ushort4*)out + i) = make_ushort4(f2bf(v.x), f2bf(v.y), f2bf(v.z), f2bf(v.w));
}

// ---------------- parallel folds: wave per output ----------------
__global__ __launch_bounds__(256) void fold_ws_kernel(const float* __restrict__ gat_W,
    const float* __restrict__ att_src, const float* __restrict__ att_dst,
    float* __restrict__ ws_att, int L){
  int wave = threadIdx.x >> 6, lane = threadIdx.x & 63;
  int idx = blockIdx.x*4 + wave;
  if (idx >= L*DD*8) return;
  int j = idx & 7; int k = (idx >> 3) & 127; int l = idx >> 10;
  int h = j & 3;
  const float* att = (j < 4) ? att_src : att_dst;
  const float* av = att + (size_t)(l*NHEAD + h)*DD;
  const float* Wl = gat_W + (size_t)l*DD*HDIM + (size_t)k*HDIM + h*DD;
  float acc = Wl[lane]*av[lane] + Wl[lane + 64]*av[lane + 64];
  acc = waveReduceSum(acc);
  if (lane == 0) ws_att[idx] = acc;
}

__global__ __launch_bounds__(256) void fold_we_kernel(const float* __restrict__ gat_We,
    const float* __restrict__ att_edge, float* __restrict__ we_att, int L){
  int wave = threadIdx.x >> 6, lane = threadIdx.x & 63;
  int idx = blockIdx.x*4 + wave;
  if (idx >= L*EFEAT*NHEAD) return;
  int h = idx & 3; int f = (idx >> 2) & 31; int l = idx >> 7;
  const float* av = att_edge + (size_t)(l*NHEAD + h)*DD;
  const float* Wel = gat_We + (size_t)l*EFEAT*HDIM + (size_t)f*HDIM + h*DD;
  float acc = Wel[lane]*av[lane] + Wel[lane + 64]*av[lane + 64];
  acc = waveReduceSum(acc);
  if (lane == 0) we_att[idx] = acc;
}

__global__ void fold_self_kernel(const float* __restrict__ we_att,
    const float* __restrict__ ea_sum, float invE, float* __restrict__ al_self, int L){
  int t = threadIdx.x;
  if (t >= L*NHEAD) return;
  int h = t & 3; int l = t >> 2;
  float acc = 0.f;
  for (int f = 0; f < EFEAT; f++) acc += ea_sum[f]*invE * we_att[(l*EFEAT + f)*NHEAD + h];
  al_self[t] = acc;
}

// ---------------- gat_W -> bf16 Bt[l][d][h*128+k], LDS-tiled transpose ----------------
__global__ __launch_bounds__(256) void bt_prep_kernel(const float* __restrict__ gat_W,
                                                      unsigned short* __restrict__ Bt, int LH){
  __shared__ float tile[32][33];
  int blk = blockIdx.x;
  int lh = blk >> 4;
  if (lh >= LH) return;
  int tl = blk & 15;
  int k0 = (tl & 3)*32, d0 = (tl >> 2)*32;
  int l = lh >> 2, h = lh & 3;
  const float* in = gat_W + (size_t)l*DD*HDIM + h*DD;
  unsigned short* outp = Bt + (size_t)l*DD*HDIM + h*DD;
  int tx = threadIdx.x & 31, ty = threadIdx.x >> 5;
  #pragma unroll
  for (int i = 0; i < 4; i++){
    int k = k0 + ty + i*8;
    tile[ty + i*8][tx] = in[(size_t)k*HDIM + d0 + tx];
  }
  __syncthreads();
  #pragma unroll
  for (int i = 0; i < 4; i++){
    int d = d0 + ty + i*8;
    outp[(size_t)d*HDIM + k0 + tx] = f2bf(tile[tx][ty + i*8]);
  }
}

// ---------------- embW -> bf16 transposed [128][128] ----------------
__global__ void embwt_prep_kernel(const float* __restrict__ embW,
                                  unsigned short* __restrict__ Wt){
  int i = blockIdx.x*blockDim.x + threadIdx.x;
  if (i >= DD*DD) return;
  int n = i >> 7, k = i & 127;
  Wt[i] = f2bf(embW[(size_t)k*DD + n]);
}

// ---------------- [W1a | W1b] -> bf16 transposed [256][128] ----------------
__global__ void w1ab_prep_kernel(const float* __restrict__ hW1,
                                 unsigned short* __restrict__ Bhd){
  int i = blockIdx.x*blockDim.x + threadIdx.x;
  if (i >= 256*DD) return;
  int n = i >> 7, k = i & 127;
  float v = (n < 128) ? hW1[(size_t)k*DD + n] : hW1[(size_t)(128 + k)*DD + (n - 128)];
  Bhd[i] = f2bf(v);
}

// ---------------- W1c -> MFMA B-fragment layout: Bh[c][lane][j] ----------------
__global__ void w1c_prep_kernel(const float* __restrict__ W1c, unsigned short* __restrict__ Bh){
  int i = blockIdx.x*blockDim.x + threadIdx.x;
  if (i >= 8*64*8) return;
  int j = i & 7, lane = (i >> 3) & 63, c = i >> 9;
  int ln15 = lane & 15, quad = lane >> 4;
  int k = quad*8 + j, n = c*16 + ln15;
  Bh[i] = f2bf(W1c[(size_t)k*DD + n]);
}

// ---------------- unified MFMA GEMM + fused epilogues ----------------
// Two-phase staging (batch loads -> regs -> ds_write) + double-buffered LDS
// (NCH>1) + next-chunk A prefetch: keeps ~8-12 loads in flight per wave
// instead of a serial load->ds_write chain (the R10 47us bottleneck).
template<int KD, int NOUT>
__global__ __launch_bounds__(256, 4) void gemm_fused_kernel(
    const unsigned short* __restrict__ A, const unsigned short* __restrict__ Bt,
    const float* __restrict__ bias, float scale, int relu, int mode,
    const float* __restrict__ ln_scale, const float* __restrict__ ln_bias,
    const float* __restrict__ gamma, const float* __restrict__ beta,
    const float* __restrict__ ws_att,
    unsigned short* __restrict__ hm_bf, float* __restrict__ al_s,
    float* __restrict__ al_d, unsigned short* __restrict__ outbf, int N){
  constexpr int NC = NOUT/16;
  constexpr int NCH = KD/128;
  constexpr int NB = (NCH > 1) ? 2 : 1;            // double-buffer only if pipelined
  constexpr int GRP = (NC > 8) ? 8 : NC;           // staging reg-batch size
  __shared__ unsigned short Bs[NB][NC*2048];       // per buffer: 4ks x NC x 64 lanes x 8
  __shared__ float s_att[8*DD];
  __shared__ float sP[4][DD];
  int t = threadIdx.x;
  if (mode == 0){
    for (int i = t; i < DD*8; i += 256){
      int col = i & 127, j = i >> 7;
      s_att[j*DD + col] = ws_att[col*8 + j];
    }
    for (int i = t; i < DD; i += 256){
      sP[0][i] = ln_scale[i]; sP[1][i] = ln_bias[i];
      sP[2][i] = gamma[i];    sP[3][i] = beta[i];
    }
  }
  int wave = t >> 6, lane = t & 63;
  int ln15 = lane & 15, quad = lane >> 4;
  int row0 = blockIdx.x*64 + wave*16;
  int arow = row0 + ln15;
  if (arow > N - 1) arow = N - 1;
  const unsigned short* aptr = A + (size_t)arow*KD;

  f32x4 acc[NC];
  #pragma unroll
  for (int c = 0; c < NC; c++) acc[c] = (f32x4)(0.f);

  // ---- stage chunk 0 (two-phase: batch loads, then batch ds_writes) ----
  {
    #pragma unroll
    for (int g0 = 0; g0 < NC/GRP; g0++){
      uint4 tmp[GRP];
      #pragma unroll
      for (int i = 0; i < GRP; i++){
        int g = (g0*GRP + i)*256 + t;
        int gl = g & 63;
        int gidx = g >> 6;
        int gc = gidx % NC, gks = gidx / NC;
        tmp[i] = *(const uint4*)(Bt + (size_t)(gc*16 + (gl & 15))*KD
                                 + gks*32 + (gl >> 4)*8);
      }
      #pragma unroll
      for (int i = 0; i < GRP; i++){
        int g = (g0*GRP + i)*256 + t;
        *(uint4*)&Bs[0][(size_t)g*8] = tmp[i];
      }
    }
  }
  // A-fragments for chunk 0
  s16x8 afn[4];
  #pragma unroll
  for (int ks = 0; ks < 4; ks++)
    afn[ks] = *(const s16x8*)(aptr + ks*32 + quad*8);

  for (int ch = 0; ch < NCH; ch++){
    __syncthreads();   // staged buf[ch&1] now visible to all waves
    uint4 tmp[GRP*(NC/GRP)];   // regs for next chunk's B (NC frags)
    if (ch + 1 < NCH){
      #pragma unroll
      for (int i = 0; i < NC; i++){
        int g = i*256 + t;
        int gl = g & 63;
        int gidx = g >> 6;
        int gc = gidx % NC, gks = gidx / NC;
        tmp[i] = *(const uint4*)(Bt + (size_t)(gc*16 + (gl & 15))*KD
                                 + (ch + 1)*128 + gks*32 + (gl >> 4)*8);
      }
    }
    s16x8 afc[4];
    #pragma unroll
    for (int ks = 0; ks < 4; ks++) afc[ks] = afn[ks];
    if (ch + 1 < NCH){
      #pragma unroll
      for (int ks = 0; ks < 4; ks++)
        afn[ks] = *(const s16x8*)(aptr + (ch + 1)*128 + ks*32 + quad*8);
    }
    // compute on buf[ch&1] while next chunk's global loads are in flight
    const unsigned short* bsrd = Bs[ch & (NB - 1)];
    #pragma unroll
    for (int ks = 0; ks < 4; ks++){
      #pragma unroll
      for (int c = 0; c < NC; c++){
        s16x8 b = *(const s16x8*)&bsrd[(size_t)((ks*NC + c)*64 + lane)*8];
        acc[c] = __builtin_amdgcn_mfma_f32_16x16x32_bf16(afc[ks], b, acc[c], 0, 0, 0);
      }
    }
    if (ch + 1 < NCH){
      unsigned short* bswr = (unsigned short*)Bs[(ch + 1) & (NB - 1)];
      #pragma unroll
      for (int i = 0; i < NC; i++){
        int g = i*256 + t;
        *(uint4*)&bswr[(size_t)g*8] = tmp[i];
      }
    }
  }

  float bv[NC];
  #pragma unroll
  for (int c = 0; c < NC; c++){
    if constexpr (NOUT == 256) bv[c] = (c < 8) ? bias[c*16 + ln15] : 0.f;
    else bv[c] = bias[c*16 + ln15];
  }

  #pragma unroll
  for (int r = 0; r < 4; r++){
    int row = row0 + quad*4 + r;
    bool valid = (row < N);
    float hv[NC];
    #pragma unroll
    for (int c = 0; c < NC; c++){
      float v = scale*acc[c][r] + bv[c];
      hv[c] = relu ? fmaxf(v, 0.f) : v;
    }
    if (mode == 1){
      if (valid){
        #pragma unroll
        for (int c = 0; c < NC; c++)
          outbf[(size_t)row*NOUT + c*16 + ln15] = f2bf(hv[c]);
      }
      continue;
    }
    if constexpr (NOUT == 128){
      float sum = 0.f;
      #pragma unroll
      for (int c = 0; c < NC; c++) sum += hv[c];
      sum = quadReduceSum(sum);
      float mu = sum * (1.f/128.f);
      float vs = 0.f;
      #pragma unroll
      for (int c = 0; c < NC; c++){ float d = hv[c] - mu; vs += d*d; }
      vs = quadReduceSum(vs);
      float rstd = rsqrtf(vs*(1.f/128.f) + 1e-5f);
      float m[NC];
      #pragma unroll
      for (int c = 0; c < NC; c++){
        int col = c*16 + ln15;
        float hn = (hv[c] - mu)*rstd*sP[0][col] + sP[1][col];
        m[c] = sP[2][col]*hn + sP[3][col];
        if (valid) hm_bf[(size_t)row*DD + col] = f2bf(m[c]);
      }
      float alv[8];
      #pragma unroll
      for (int j = 0; j < 8; j++){
        float a = 0.f;
        #pragma unroll
        for (int c = 0; c < NC; c++) a += m[c]*s_att[j*DD + c*16 + ln15];
        alv[j] = quadReduceSum(a);
      }
      if (ln15 == 0 && valid){
        *(float4*)&al_s[(size_t)row*4] = make_float4(alv[0], alv[1], alv[2], alv[3]);
        *(float4*)&al_d[(size_t)row*4] = make_float4(alv[4], alv[5], alv[6], alv[7]);
      }
    }
  }
}

// ---------------- edge-parallel softmax weights in CSR order (no max shift) ------------
__global__ __launch_bounds__(256) void edge_logit_kernel(
    const unsigned short* __restrict__ eap, const float* __restrict__ al_s,
    const float* __restrict__ al_d, const int2* __restrict__ sd,
    const float* __restrict__ we_att, float* __restrict__ wbuf, int E){
  __shared__ float4 swe[EFEAT];
  int t = threadIdx.x;
  if (t < EFEAT) swe[t] = *(const float4*)&we_att[t*4];
  __syncthreads();
  int p = blockIdx.x*256 + t;
  if (p >= E) return;
  int2 e2 = sd[p];
  float4 as = *(const float4*)&al_s[(size_t)e2.x*4];
  float4 ad = *(const float4*)&al_d[(size_t)e2.y*4];
  float a0 = as.x + ad.x, a1 = as.y + ad.y, a2 = as.z + ad.z, a3 = as.w + ad.w;
  const uint4* ep = (const uint4*)(eap + (size_t)p*EFEAT);
  #pragma unroll
  for (int q = 0; q < 4; q++){
    uint4 u = ep[q];
    unsigned arr[4] = {u.x, u.y, u.z, u.w};
    #pragma unroll
    for (int j = 0; j < 4; j++){
      float x0 = bf2f((unsigned short)(arr[j] & 0xffff));
      float x1 = bf2f((unsigned short)(arr[j] >> 16));
      float4 w0 = swe[q*8 + j*2], w1 = swe[q*8 + j*2 + 1];
      a0 += x0*w0.x + x1*w1.x;
      a1 += x0*w0.y + x1*w1.y;
      a2 += x0*w0.z + x1*w1.z;
      a3 += x0*w0.w + x1*w1.w;
    }
  }
  *(float4*)&wbuf[(size_t)p*4] = make_float4(__expf(lrelu(a0)), __expf(lrelu(a1)),
                                             __expf(lrelu(a2)), __expf(lrelu(a3)));
}

// ---------------- single-pass weighted aggregation (block per node, 64 threads) --------
__global__ __launch_bounds__(64) void aggregate3_kernel(
    const unsigned short* __restrict__ hm_bf, const float* __restrict__ wbuf,
    const float* __restrict__ al_s, const float* __restrict__ al_d,
    const float* __restrict__ al_self4, const int* __restrict__ offs,
    const int2* __restrict__ sd, unsigned short* __restrict__ z, int N){
  int n = blockIdx.x, t = threadIdx.x;
  int beg = offs[n], end = offs[n + 1];
  float4 aslf = *(const float4*)al_self4;
  float4 asn = *(const float4*)&al_s[(size_t)n*4];
  float4 adn = *(const float4*)&al_d[(size_t)n*4];
  float e0 = __expf(lrelu(asn.x + adn.x + aslf.x));
  float e1 = __expf(lrelu(asn.y + adn.y + aslf.y));
  float e2 = __expf(lrelu(asn.z + adn.z + aslf.z));
  float e3 = __expf(lrelu(asn.w + adn.w + aslf.w));
  ushort2 hv = *((const ushort2*)(hm_bf + (size_t)n*DD) + t);
  float h0 = bf2f(hv.x), h1 = bf2f(hv.y);
  float ac00 = e0*h0, ac01 = e0*h1;
  float ac10 = e1*h0, ac11 = e1*h1;
  float ac20 = e2*h0, ac21 = e2*h1;
  float ac30 = e3*h0, ac31 = e3*h1;
  float den0 = e0, den1 = e1, den2 = e2, den3 = e3;
  int p = beg;
  for (; p + 2 <= end; p += 2){
    int sA = sd[p].x, sB = sd[p + 1].x;
    float4 wA = *(const float4*)&wbuf[(size_t)p*4];
    float4 wB = *(const float4*)&wbuf[(size_t)(p + 1)*4];
    ushort2 vA = *((const ushort2*)(hm_bf + (size_t)sA*DD) + t);
    ushort2 vB = *((const ushort2*)(hm_bf + (size_t)sB*DD) + t);
    float vA0 = bf2f(vA.x), vA1 = bf2f(vA.y);
    float vB0 = bf2f(vB.x), vB1 = bf2f(vB.y);
    ac00 += wA.x*vA0 + wB.x*vB0; ac01 += wA.x*vA1 + wB.x*vB1;
    ac10 += wA.y*vA0 + wB.y*vB0; ac11 += wA.y*vA1 + wB.y*vB1;
    ac20 += wA.z*vA0 + wB.z*vB0; ac21 += wA.z*vA1 + wB.z*vB1;
    ac30 += wA.w*vA0 + wB.w*vB0; ac31 += wA.w*vA1 + wB.w*vB1;
    den0 += wA.x + wB.x; den1 += wA.y + wB.y;
    den2 += wA.z + wB.z; den3 += wA.w + wB.w;
  }
  if (p < end){
    int s = sd[p].x;
    float4 w = *(const float4*)&wbuf[(size_t)p*4];
    ushort2 v2 = *((const ushort2*)(hm_bf + (size_t)s*DD) + t);
    float v0 = bf2f(v2.x), v1 = bf2f(v2.y);
    ac00 += w.x*v0; ac01 += w.x*v1;
    ac10 += w.y*v0; ac11 += w.y*v1;
    ac20 += w.z*v0; ac21 += w.z*v1;
    ac30 += w.w*v0; ac31 += w.w*v1;
    den0 += w.x; den1 += w.y; den2 += w.z; den3 += w.w;
  }
  float r0 = 1.f/(den0 + 1e-16f), r1 = 1.f/(den1 + 1e-16f);
  float r2 = 1.f/(den2 + 1e-16f), r3 = 1.f/(den3 + 1e-16f);
  size_t zb = (size_t)n*HDIM;
  ushort2* zp = (ushort2*)(z + zb);
  zp[0*64 + t] = make_ushort2(f2bf(ac00*r0), f2bf(ac01*r0));
  zp[1*64 + t] = make_ushort2(f2bf(ac10*r1), f2bf(ac11*r1));
  zp[2*64 + t] = make_ushort2(f2bf(ac20*r2), f2bf(ac21*r2));
  zp[3*64 + t] = make_ushort2(f2bf(ac30*r3), f2bf(ac31*r3));
}

// ---------------- MFMA edge head: out[e] = relu(p[s]+p[d]+ea@W1c)@W2 + b2 ------------
__global__ __launch_bounds__(256) void head_mfma_kernel(
    const unsigned short* __restrict__ eap, const int* __restrict__ posOf,
    const unsigned short* __restrict__ Bh, const unsigned short* __restrict__ pbuf,
    const float* __restrict__ W2, const float* __restrict__ b2,
    const int* __restrict__ srcA, const int* __restrict__ dstA,
    float* __restrict__ out, int E){
  int t = threadIdx.x;
  int wave = t >> 6, lane = t & 63;
  int ln15 = lane & 15, quad = lane >> 4;
  int e0 = (blockIdx.x*4 + wave)*16;
  if (e0 >= E) return;
  int arow = e0 + ln15;
  if (arow > E - 1) arow = E - 1;
  int ap = posOf[arow];
  s16x8 a = *(const s16x8*)(eap + (size_t)ap*EFEAT + quad*8);
  f32x4 acc[8];
  #pragma unroll
  for (int c = 0; c < 8; c++){
    s16x8 b = *(const s16x8*)(Bh + ((size_t)c*64 + lane)*8);
    acc[c] = __builtin_amdgcn_mfma_f32_16x16x32_bf16(a, b, (f32x4)(0.f), 0, 0, 0);
  }
  float w2v[8];
  #pragma unroll
  for (int c = 0; c < 8; c++) w2v[c] = W2[c*16 + ln15];
  float res[4];
  #pragma unroll
  for (int r = 0; r < 4; r++){
    int e = e0 + quad*4 + r;
    int ec = (e < E) ? e : E - 1;
    int s = srcA[ec], d = dstA[ec];
    const unsigned short* ps = pbuf + (size_t)s*256 + ln15;
    const unsigned short* pd = pbuf + (size_t)d*256 + 128 + ln15;
    float sum = 0.f;
    #pragma unroll
    for (int c = 0; c < 8; c++){
      float q = acc[c][r] + bf2f(ps[c*16]) + bf2f(pd[c*16]);
      sum += fmaxf(q, 0.f) * w2v[c];
    }
    res[r] = sum;
  }
  #pragma unroll
  for (int r = 0; r < 4; r++){
    float v = res[r];
    v += __shfl_xor(v, 1, 64); v += __shfl_xor(v, 2, 64);
    v += __shfl_xor(v, 4, 64); v += __shfl_xor(v, 8, 64);
    res[r] = v;
  }
  if (ln15 == 0){
    float bb = b2[0];
    #pragma unroll
    for (int r = 0; r < 4; r++){
      int e = e0 + quad*4 + r;
      if (e < E) out[e] = res[r] + bb;
    }
  }
}

extern "C" void kernel_launch(void* const* d_in, const int* in_sizes, int n_in,
                              void* d_out, int out_size, void* d_ws, size_t ws_size,
                              hipStream_t stream){
  const float* x      = (const float*)d_in[0];
  const int*   eidx   = (const int*)d_in[1];
  const float* eattr  = (const float*)d_in[2];
  const float* gamma  = (const float*)d_in[3];
  const float* beta   = (const float*)d_in[4];
  const float* embW   = (const float*)d_in[5];
  const float* embB   = (const float*)d_in[6];
  const float* lnS    = (const float*)d_in[7];
  const float* lnB    = (const float*)d_in[8];
  const float* gatW   = (const float*)d_in[9];
  const float* attS   = (const float*)d_in[10];
  const float* attD   = (const float*)d_in[11];
  const float* gatWe  = (const float*)d_in[12];
  const float* attE   = (const float*)d_in[13];
  const float* gatB   = (const float*)d_in[14];
  const float* hW1    = (const float*)d_in[15];
  const float* hB1    = (const float*)d_in[16];
  const float* hW2    = (const float*)d_in[17];
  const float* hB2    = (const float*)d_in[18];
  float* out = (float*)d_out;

  int N = in_sizes[0] / DD;
  int E = in_sizes[1] / 2;
  int L = in_sizes[3] / DD;
  int Npad = (N + 63) & ~63;

  const int* srcA = eidx;
  const int* dstA = eidx + E;

  float* ws = (float*)d_ws;
  float* ea_sum  = ws + 0;
  float* we_att  = ws + 64;
  float* al_self = ws + 1024;
  float* ws_att  = ws + 2048;
  size_t o = 8192;
  int* deg    = (int*)(ws + o); o += N;
  int* offs   = (int*)(ws + o); o += N + 1;
  int* cursor = (int*)(ws + o); o += N;
  o = (o + 1) & ~(size_t)1;
  int2* sd    = (int2*)(ws + o); o += (size_t)E*2;
  int* posOf  = (int*)(ws + o); o += E;
  o = (o + 255) & ~(size_t)255;
  unsigned short* Bt  = (unsigned short*)(ws + o); o += (size_t)L*DD*HDIM/2;
  unsigned short* Bh  = (unsigned short*)(ws + o); o += 8*64*8/2;
  unsigned short* Wte = (unsigned short*)(ws + o); o += DD*DD/2;
  unsigned short* Bhd = (unsigned short*)(ws + o); o += 256*DD/2;
  unsigned short* xbf = (unsigned short*)(ws + o); o += (size_t)N*DD/2;
  unsigned short* hm_bf = (unsigned short*)(ws + o); o += (size_t)N*DD/2;
  float* al_s  = ws + o; o += (size_t)N*4;
  float* al_d  = ws + o; o += (size_t)N*4;
  unsigned short* eap = (unsigned short*)(ws + o); o += (size_t)E*EFEAT/2;
  float* wbuf  = ws + o; o += (size_t)E*4;
  unsigned short* z = (unsigned short*)(ws + o); o += (size_t)Npad*HDIM/2;
  unsigned short* hbf  = hm_bf;
  unsigned short* pbuf = z;

  hipMemsetAsync(ea_sum, 0, EFEAT*sizeof(float), stream);
  hipMemsetAsync(deg, 0, (size_t)N*sizeof(int), stream);
  ea_sum4_kernel<<<1024, 256, 0, stream>>>(eattr, ea_sum, E);
  hist_kernel<<<(E + 255)/256, 256, 0, stream>>>(dstA, deg, E);
  scan_kernel<<<1, 1024, 0, stream>>>(deg, offs, N);
  hipMemcpyAsync(cursor, offs, (size_t)N*sizeof(int), hipMemcpyDeviceToDevice, stream);
  scatter_kernel<<<(E + 255)/256, 256, 0, stream>>>(dstA, srcA, cursor, sd, posOf, E);
  eap_prep_kernel<<<(E*8 + 255)/256, 256, 0, stream>>>(eattr, posOf, eap, E);
  fold_ws_kernel<<<(L*DD*8 + 3)/4, 256, 0, stream>>>(gatW, attS, attD, ws_att, L);
  fold_we_kernel<<<(L*EFEAT*NHEAD + 3)/4, 256, 0, stream>>>(gatWe, attE, we_att, L);
  fold_self_kernel<<<1, 64, 0, stream>>>(we_att, ea_sum, 1.0f/(float)E, al_self, L);
  bt_prep_kernel<<<L*NHEAD*16, 256, 0, stream>>>(gatW, Bt, L*NHEAD);
  embwt_prep_kernel<<<(DD*DD + 255)/256, 256, 0, stream>>>(embW, Wte);
  w1ab_prep_kernel<<<(256*DD + 255)/256, 256, 0, stream>>>(hW1, Bhd);
  w1c_prep_kernel<<<(8*64*8 + 255)/256, 256, 0, stream>>>(hW1 + 2*DD*DD, Bh);
  bf16_conv_kernel<<<(N*DD/4 + 255)/256, 256, 0, stream>>>(x, xbf, N*DD/4);

  // embed + LN/FiLM/al (layer 0)
  gemm_fused_kernel<128,128><<<(N + 63)/64, 256, 0, stream>>>(
      xbf, Wte, embB, 1.0f, 0, 0, lnS, lnB, gamma, beta, ws_att,
      hm_bf, al_s, al_d, nullptr, N);

  for (int l = 0; l < L; l++){
    edge_logit_kernel<<<(E + 255)/256, 256, 0, stream>>>(eap, al_s, al_d, sd,
        we_att + (size_t)l*EFEAT*NHEAD, wbuf, E);
    aggregate3_kernel<<<N, 64, 0, stream>>>(hm_bf, wbuf, al_s, al_d,
        al_self + (size_t)l*NHEAD, offs, sd, z, N);
    if (l < L - 1){
      gemm_fused_kernel<512,128><<<(N + 63)/64, 256, 0, stream>>>(
          z, Bt + (size_t)l*DD*HDIM, gatB + (size_t)l*DD, 0.25f, 1, 0,
          lnS + (l+1)*DD, lnB + (l+1)*DD, gamma + (l+1)*DD, beta + (l+1)*DD,
          ws_att + (size_t)(l+1)*DD*8, hm_bf, al_s, al_d, nullptr, N);
    } else {
      gemm_fused_kernel<512,128><<<(N + 63)/64, 256, 0, stream>>>(
          z, Bt + (size_t)l*DD*HDIM, gatB + (size_t)l*DD, 0.25f, 1, 1,
          nullptr, nullptr, nullptr, nullptr, nullptr,
          nullptr, nullptr, nullptr, hbf, N);
    }
  }

  // head pre-projection: pbuf[N,256] = hbf @ [W1a|W1b] (+hB1 on cols<128)
  gemm_fused_kernel<128,256><<<(N + 63)/64, 256, 0, stream>>>(
      hbf, Bhd, hB1, 1.0f, 0, 1, nullptr, nullptr, nullptr, nullptr, nullptr,
      nullptr, nullptr, nullptr, pbuf, N);

  head_mfma_kernel<<<(E + 63)/64, 256, 0, stream>>>(eap, posOf, Bh, pbuf,
      hW2, hB2, srcA, dstA, out, E);
}